// Round 1
// baseline (3813.272 us; speedup 1.0000x reference)
//
#include <hip/hip_runtime.h>

// Model dims (fixed by the reference)
#define S_DIM   6
#define H_DIM   20
#define F_INN   8
#define N_OUTC  20
#define G_DIM   32
#define D1_DIM  16
#define NGRAPH  512

__device__ __forceinline__ void fadd_atomic(float* p, float v) {
    unsafeAtomicAdd(p, v);   // native global_atomic_add_f32 on gfx950
}

// ---------------------------------------------------------------------------
// Fused ECC edge kernel: per-edge MLP (S->H->H->F_IN*N_OUT) + einsum with
// x[col] + scatter-add into agg[row], plus integer degree count.
// Weight indices are wave-uniform -> scalar loads (s_load) expected.
// ---------------------------------------------------------------------------
__global__ __launch_bounds__(256) void ecc_edge_kernel(
    const float* __restrict__ e, const float* __restrict__ x,
    const int* __restrict__ ei, int E,
    const float* __restrict__ w1, const float* __restrict__ b1,
    const float* __restrict__ w2, const float* __restrict__ b2,
    const float* __restrict__ w3, const float* __restrict__ b3,
    float* __restrict__ agg, int* __restrict__ deg)
{
    int i = blockIdx.x * 256 + threadIdx.x;
    if (i >= E) return;
    int r = ei[i];
    int c = ei[E + i];

    float ef[S_DIM];
#pragma unroll
    for (int s = 0; s < S_DIM; ++s) ef[s] = e[i * S_DIM + s];

    // h1 = relu(e @ w1 + b1)
    float h1[H_DIM];
#pragma unroll
    for (int j = 0; j < H_DIM; ++j) {
        float a = b1[j];
#pragma unroll
        for (int s = 0; s < S_DIM; ++s) a = fmaf(ef[s], w1[s * H_DIM + j], a);
        h1[j] = fmaxf(a, 0.0f);
    }

    // h2 = relu(h1 @ w2 + b2)
    float h2[H_DIM];
#pragma unroll
    for (int j = 0; j < H_DIM; ++j) {
        float a = b2[j];
#pragma unroll
        for (int k = 0; k < H_DIM; ++k) a = fmaf(h1[k], w2[k * H_DIM + j], a);
        h2[j] = fmaxf(a, 0.0f);
    }

    // msg[o] = sum_f x[col,f] * (b3[f,o] + sum_k h2[k]*w3[k, f*N_OUT+o])
    float msg[N_OUTC];
#pragma unroll
    for (int o = 0; o < N_OUTC; ++o) msg[o] = 0.0f;

    for (int f = 0; f < F_INN; ++f) {           // rolled: f is uniform
        float xf = x[c * F_INN + f];
#pragma unroll
        for (int o = 0; o < N_OUTC; ++o) {
            float w = b3[f * N_OUTC + o];
#pragma unroll
            for (int k = 0; k < H_DIM; ++k)
                w = fmaf(h2[k], w3[k * (F_INN * N_OUTC) + f * N_OUTC + o], w);
            msg[o] = fmaf(xf, w, msg[o]);
        }
    }

    atomicAdd(&deg[r], 1);
#pragma unroll
    for (int o = 0; o < N_OUTC; ++o) fadd_atomic(&agg[r * N_OUTC + o], msg[o]);
}

// ---------------------------------------------------------------------------
// Node kernel 1: x1 = relu(agg + x@root + b); dinv = rsqrt(deg+1); hw1 = x1@gcn1_w
// ---------------------------------------------------------------------------
__global__ __launch_bounds__(256) void node1_kernel(
    const float* __restrict__ agg, const float* __restrict__ x,
    const int* __restrict__ deg, int N,
    const float* __restrict__ root, const float* __restrict__ eb,
    const float* __restrict__ g1w,
    float* __restrict__ dinv, float* __restrict__ hw1)
{
    int n = blockIdx.x * 256 + threadIdx.x;
    if (n >= N) return;

    float d = (float)deg[n] + 1.0f;
    float di = rsqrtf(d);
    dinv[n] = di;

    float xf[F_INN];
#pragma unroll
    for (int f = 0; f < F_INN; ++f) xf[f] = x[n * F_INN + f];

    float x1[N_OUTC];
#pragma unroll
    for (int o = 0; o < N_OUTC; ++o) {
        float a = agg[n * N_OUTC + o] + eb[o];
#pragma unroll
        for (int f = 0; f < F_INN; ++f) a = fmaf(xf[f], root[f * N_OUTC + o], a);
        x1[o] = fmaxf(a, 0.0f);
    }

#pragma unroll
    for (int g = 0; g < G_DIM; ++g) {
        float a = 0.0f;
#pragma unroll
        for (int o = 0; o < N_OUTC; ++o) a = fmaf(x1[o], g1w[o * G_DIM + g], a);
        hw1[n * G_DIM + g] = a;
    }
}

// ---------------------------------------------------------------------------
// GCN scatter: nmsg[row] += dinv[row]*dinv[col] * hw[col]   (32 channels)
// ---------------------------------------------------------------------------
__global__ __launch_bounds__(256) void gcn_scatter_kernel(
    const int* __restrict__ ei, int E,
    const float* __restrict__ dinv, const float* __restrict__ hw,
    float* __restrict__ nmsg)
{
    int i = blockIdx.x * 256 + threadIdx.x;
    if (i >= E) return;
    int r = ei[i];
    int c = ei[E + i];
    float w = dinv[r] * dinv[c];

#pragma unroll
    for (int g = 0; g < G_DIM; g += 4) {
        const float4 v = *(const float4*)&hw[c * G_DIM + g];
        fadd_atomic(&nmsg[r * G_DIM + g + 0], w * v.x);
        fadd_atomic(&nmsg[r * G_DIM + g + 1], w * v.y);
        fadd_atomic(&nmsg[r * G_DIM + g + 2], w * v.z);
        fadd_atomic(&nmsg[r * G_DIM + g + 3], w * v.w);
    }
}

// ---------------------------------------------------------------------------
// Node kernel 2: x2 = relu(nmsg1 + dinv^2*hw1 + b); hw2 = x2@gcn2_w
// ---------------------------------------------------------------------------
__global__ __launch_bounds__(256) void node2_kernel(
    const float* __restrict__ nmsg1, const float* __restrict__ hw1,
    const float* __restrict__ dinv, int N,
    const float* __restrict__ g1b, const float* __restrict__ g2w,
    float* __restrict__ hw2)
{
    int n = blockIdx.x * 256 + threadIdx.x;
    if (n >= N) return;
    float sn = dinv[n] * dinv[n];

    float x2[G_DIM];
#pragma unroll
    for (int g = 0; g < G_DIM; ++g) {
        float a = nmsg1[n * G_DIM + g] + sn * hw1[n * G_DIM + g] + g1b[g];
        x2[g] = fmaxf(a, 0.0f);
    }
#pragma unroll
    for (int g2 = 0; g2 < G_DIM; ++g2) {
        float a = 0.0f;
#pragma unroll
        for (int g = 0; g < G_DIM; ++g) a = fmaf(x2[g], g2w[g * G_DIM + g2], a);
        hw2[n * G_DIM + g2] = a;
    }
}

// ---------------------------------------------------------------------------
// Node kernel 3: x3 = relu(nmsg2 + dinv^2*hw2 + b); pooled[seg[n]] += x3
// ---------------------------------------------------------------------------
__global__ __launch_bounds__(256) void node3_kernel(
    const float* __restrict__ nmsg2, const float* __restrict__ hw2,
    const float* __restrict__ dinv, const int* __restrict__ seg, int N,
    const float* __restrict__ g2b,
    float* __restrict__ pooled)
{
    int n = blockIdx.x * 256 + threadIdx.x;
    if (n >= N) return;
    float sn = dinv[n] * dinv[n];
    int s = seg[n];

#pragma unroll
    for (int g = 0; g < G_DIM; ++g) {
        float a = nmsg2[n * G_DIM + g] + sn * hw2[n * G_DIM + g] + g2b[g];
        a = fmaxf(a, 0.0f);
        fadd_atomic(&pooled[s * G_DIM + g], a);
    }
}

// ---------------------------------------------------------------------------
// Head: out = (pooled @ d1_w + d1_b) @ d2_w + d2_b
// ---------------------------------------------------------------------------
__global__ __launch_bounds__(256) void head_kernel(
    const float* __restrict__ pooled,
    const float* __restrict__ d1w, const float* __restrict__ d1b,
    const float* __restrict__ d2w, const float* __restrict__ d2b,
    float* __restrict__ out, int ngraph)
{
    int i = blockIdx.x * 256 + threadIdx.x;
    if (i >= ngraph) return;

    float p[G_DIM];
#pragma unroll
    for (int g = 0; g < G_DIM; ++g) p[g] = pooled[i * G_DIM + g];

    float acc = d2b[0];
#pragma unroll
    for (int j = 0; j < D1_DIM; ++j) {
        float t = d1b[j];
#pragma unroll
        for (int g = 0; g < G_DIM; ++g) t = fmaf(p[g], d1w[g * D1_DIM + j], t);
        acc = fmaf(t, d2w[j], acc);
    }
    out[i] = acc;
}

// ---------------------------------------------------------------------------
extern "C" void kernel_launch(void* const* d_in, const int* in_sizes, int n_in,
                              void* d_out, int out_size, void* d_ws, size_t ws_size,
                              hipStream_t stream)
{
    const float* x    = (const float*)d_in[0];
    const float* e    = (const float*)d_in[1];
    const int*   ei   = (const int*)d_in[2];
    const int*   seg  = (const int*)d_in[3];
    const float* w1   = (const float*)d_in[4];
    const float* b1   = (const float*)d_in[5];
    const float* w2   = (const float*)d_in[6];
    const float* b2   = (const float*)d_in[7];
    const float* w3   = (const float*)d_in[8];
    const float* b3   = (const float*)d_in[9];
    const float* root = (const float*)d_in[10];
    const float* eb   = (const float*)d_in[11];
    const float* g1w  = (const float*)d_in[12];
    const float* g1b  = (const float*)d_in[13];
    const float* g2w  = (const float*)d_in[14];
    const float* g2b  = (const float*)d_in[15];
    const float* d1w  = (const float*)d_in[16];
    const float* d1b  = (const float*)d_in[17];
    const float* d2w  = (const float*)d_in[18];
    const float* d2b  = (const float*)d_in[19];

    const int N = in_sizes[3];            // 50000
    const int E = in_sizes[1] / S_DIM;    // 800000
    float* out = (float*)d_out;

    // Workspace layout (floats). Zeroed region first.
    float* ws = (float*)d_ws;
    size_t off = 0;
    float* agg    = ws + off; off += (size_t)N * N_OUTC;   // 1,000,000
    float* nmsg1  = ws + off; off += (size_t)N * G_DIM;    // 1,600,000
    float* nmsg2  = ws + off; off += (size_t)N * G_DIM;    // 1,600,000
    float* pooled = ws + off; off += (size_t)NGRAPH * G_DIM; // 16,384
    int*   deg    = (int*)(ws + off); off += (size_t)N;    // 50,000
    size_t zero_floats = off;
    float* dinv   = ws + off; off += (size_t)N;
    float* hw1    = ws + off; off += (size_t)N * G_DIM;
    float* hw2    = ws + off; off += (size_t)N * G_DIM;
    (void)ws_size;

    hipMemsetAsync(d_ws, 0, zero_floats * sizeof(float), stream);

    int ebl = (E + 255) / 256;
    int nbl = (N + 255) / 256;

    ecc_edge_kernel<<<ebl, 256, 0, stream>>>(e, x, ei, E, w1, b1, w2, b2, w3, b3,
                                             agg, deg);
    node1_kernel<<<nbl, 256, 0, stream>>>(agg, x, deg, N, root, eb, g1w, dinv, hw1);
    gcn_scatter_kernel<<<ebl, 256, 0, stream>>>(ei, E, dinv, hw1, nmsg1);
    node2_kernel<<<nbl, 256, 0, stream>>>(nmsg1, hw1, dinv, N, g1b, g2w, hw2);
    gcn_scatter_kernel<<<ebl, 256, 0, stream>>>(ei, E, dinv, hw2, nmsg2);
    node3_kernel<<<nbl, 256, 0, stream>>>(nmsg2, hw2, dinv, seg, N, g2b, pooled);
    head_kernel<<<(NGRAPH + 255) / 256, 256, 0, stream>>>(pooled, d1w, d1b, d2w, d2b,
                                                          out, NGRAPH);
}

// Round 2
// 490.877 us; speedup vs baseline: 7.7683x; 7.7683x over previous
//
#include <hip/hip_runtime.h>

// Model dims (fixed by the reference)
#define S_DIM   6
#define H_DIM   20
#define F_INN   8
#define N_OUTC  20
#define G_DIM   32
#define D1_DIM  16
#define NGRAPH  512

// ---------------------------------------------------------------------------
// 1) Degree histogram over rows (int atomics only)
// ---------------------------------------------------------------------------
__global__ __launch_bounds__(256) void hist_kernel(
    const int* __restrict__ ei, int E, int* __restrict__ deg)
{
    int i = blockIdx.x * 256 + threadIdx.x;
    if (i >= E) return;
    atomicAdd(&deg[ei[i]], 1);
}

// ---------------------------------------------------------------------------
// 2) Single-block exclusive scan of deg -> rowptr; also dinv = rsqrt(deg+1)
// ---------------------------------------------------------------------------
__global__ __launch_bounds__(1024) void scan_kernel(
    const int* __restrict__ deg, int N, int E,
    int* __restrict__ rowptr, float* __restrict__ dinv)
{
    __shared__ int part[1024];
    int t = threadIdx.x;
    int C = (N + 1023) / 1024;
    int lo = t * C;
    int hi = min(lo + C, N);

    int s = 0;
    for (int i = lo; i < hi; ++i) s += deg[i];
    part[t] = s;
    __syncthreads();

    // Hillis-Steele inclusive scan over 1024 partials
    for (int d = 1; d < 1024; d <<= 1) {
        int v = (t >= d) ? part[t - d] : 0;
        __syncthreads();
        part[t] += v;
        __syncthreads();
    }
    int run = part[t] - s;   // exclusive prefix for this chunk

    for (int i = lo; i < hi; ++i) {
        rowptr[i] = run;
        int d = deg[i];
        run += d;
        dinv[i] = rsqrtf((float)d + 1.0f);
    }
    if (t == 1023) rowptr[N] = E;
}

// ---------------------------------------------------------------------------
// 3) Graph boundary pointers via binary search on sorted seg
// ---------------------------------------------------------------------------
__global__ __launch_bounds__(256) void gptr_kernel(
    const int* __restrict__ seg, int N, int* __restrict__ gptr)
{
    int g = blockIdx.x * 256 + threadIdx.x;
    if (g > NGRAPH) return;
    int lo = 0, hi = N;
    while (lo < hi) {
        int m = (lo + hi) >> 1;
        if (seg[m] < g) lo = m + 1; else hi = m;
    }
    gptr[g] = lo;
}

// ---------------------------------------------------------------------------
// 4) Fused ECC edge kernel: per-edge MLP + einsum with x[col]; writes the
//    20-float message into its CSR slot (no fp32 atomics; 1 int atomic/edge).
// ---------------------------------------------------------------------------
__global__ __launch_bounds__(256) void ecc_edge_kernel(
    const float* __restrict__ e, const float* __restrict__ x,
    const int* __restrict__ ei, int E,
    const float* __restrict__ w1, const float* __restrict__ b1,
    const float* __restrict__ w2, const float* __restrict__ b2,
    const float* __restrict__ w3, const float* __restrict__ b3,
    const int* __restrict__ rowptr, int* __restrict__ cnt,
    float* __restrict__ msg_sorted, int* __restrict__ col_sorted)
{
    int i = blockIdx.x * 256 + threadIdx.x;
    if (i >= E) return;
    int r = ei[i];
    int c = ei[E + i];

    float ef[S_DIM];
#pragma unroll
    for (int s = 0; s < S_DIM; ++s) ef[s] = e[i * S_DIM + s];

    // h1 = relu(e @ w1 + b1)
    float h1[H_DIM];
#pragma unroll
    for (int j = 0; j < H_DIM; ++j) {
        float a = b1[j];
#pragma unroll
        for (int s = 0; s < S_DIM; ++s) a = fmaf(ef[s], w1[s * H_DIM + j], a);
        h1[j] = fmaxf(a, 0.0f);
    }

    // h2 = relu(h1 @ w2 + b2)
    float h2[H_DIM];
#pragma unroll
    for (int j = 0; j < H_DIM; ++j) {
        float a = b2[j];
#pragma unroll
        for (int k = 0; k < H_DIM; ++k) a = fmaf(h1[k], w2[k * H_DIM + j], a);
        h2[j] = fmaxf(a, 0.0f);
    }

    // x[col] as two float4
    const float4* xp = (const float4*)&x[(size_t)c * F_INN];
    float4 xa = xp[0], xb = xp[1];
    float xf[F_INN] = {xa.x, xa.y, xa.z, xa.w, xb.x, xb.y, xb.z, xb.w};

    // msg[o] = sum_f xf[f] * (b3[f,o] + sum_k h2[k]*w3[k, f*N_OUT+o])
    float msg[N_OUTC];
#pragma unroll
    for (int o = 0; o < N_OUTC; ++o) msg[o] = 0.0f;

    for (int f = 0; f < F_INN; ++f) {           // rolled: f stays wave-uniform
        float xv = xf[f];
#pragma unroll
        for (int o = 0; o < N_OUTC; ++o) {
            float w = b3[f * N_OUTC + o];
#pragma unroll
            for (int k = 0; k < H_DIM; ++k)
                w = fmaf(h2[k], w3[k * (F_INN * N_OUTC) + f * N_OUTC + o], w);
            msg[o] = fmaf(xv, w, msg[o]);
        }
    }

    int p = rowptr[r] + atomicAdd(&cnt[r], 1);
    col_sorted[p] = c;
    float4* mp = (float4*)&msg_sorted[(size_t)p * N_OUTC];
    mp[0] = make_float4(msg[0],  msg[1],  msg[2],  msg[3]);
    mp[1] = make_float4(msg[4],  msg[5],  msg[6],  msg[7]);
    mp[2] = make_float4(msg[8],  msg[9],  msg[10], msg[11]);
    mp[3] = make_float4(msg[12], msg[13], msg[14], msg[15]);
    mp[4] = make_float4(msg[16], msg[17], msg[18], msg[19]);
}

// ---------------------------------------------------------------------------
// 5) Node kernel 1 (gather): agg = sum of CSR segment of msg_sorted;
//    x1 = relu(agg + x@root + b); hw1 = x1 @ gcn1_w
// ---------------------------------------------------------------------------
__global__ __launch_bounds__(256) void node1_kernel(
    const float* __restrict__ msg_sorted, const int* __restrict__ rowptr,
    const float* __restrict__ x, int N,
    const float* __restrict__ root, const float* __restrict__ eb,
    const float* __restrict__ g1w,
    float* __restrict__ hw1)
{
    int n = blockIdx.x * 256 + threadIdx.x;
    if (n >= N) return;
    int j0 = rowptr[n], j1 = rowptr[n + 1];

    float acc[N_OUTC];
#pragma unroll
    for (int o = 0; o < N_OUTC; ++o) acc[o] = 0.0f;

    for (int j = j0; j < j1; ++j) {
        const float4* mp = (const float4*)&msg_sorted[(size_t)j * N_OUTC];
#pragma unroll
        for (int q = 0; q < 5; ++q) {
            float4 v = mp[q];
            acc[q * 4 + 0] += v.x;
            acc[q * 4 + 1] += v.y;
            acc[q * 4 + 2] += v.z;
            acc[q * 4 + 3] += v.w;
        }
    }

    const float4* xp = (const float4*)&x[(size_t)n * F_INN];
    float4 xa = xp[0], xb = xp[1];
    float xf[F_INN] = {xa.x, xa.y, xa.z, xa.w, xb.x, xb.y, xb.z, xb.w};

    float x1[N_OUTC];
#pragma unroll
    for (int o = 0; o < N_OUTC; ++o) {
        float a = acc[o] + eb[o];
#pragma unroll
        for (int f = 0; f < F_INN; ++f) a = fmaf(xf[f], root[f * N_OUTC + o], a);
        x1[o] = fmaxf(a, 0.0f);
    }

    float4* hp = (float4*)&hw1[(size_t)n * G_DIM];
#pragma unroll
    for (int q = 0; q < G_DIM / 4; ++q) {
        float4 v;
        float* vv = &v.x;
#pragma unroll
        for (int u = 0; u < 4; ++u) {
            int g = q * 4 + u;
            float a = 0.0f;
#pragma unroll
            for (int o = 0; o < N_OUTC; ++o) a = fmaf(x1[o], g1w[o * G_DIM + g], a);
            vv[u] = a;
        }
        hp[q] = v;
    }
}

// ---------------------------------------------------------------------------
// 6) GCN layer (gather): s = sum_j dinv[col_j]*hw[col_j]; 
//    x' = relu(dinv[n]*s + dinv[n]^2*hw[n] + b); out = x' @ W2 (or x' itself)
// ---------------------------------------------------------------------------
template<bool DO_MATMUL>
__global__ __launch_bounds__(256) void gcn_gather_kernel(
    const float* __restrict__ hw, const int* __restrict__ rowptr,
    const int* __restrict__ col_sorted, const float* __restrict__ dinv, int N,
    const float* __restrict__ bias, const float* __restrict__ w2,
    float* __restrict__ outbuf)
{
    int n = blockIdx.x * 256 + threadIdx.x;
    if (n >= N) return;
    int j0 = rowptr[n], j1 = rowptr[n + 1];

    float s[G_DIM];
#pragma unroll
    for (int g = 0; g < G_DIM; ++g) s[g] = 0.0f;

    for (int j = j0; j < j1; ++j) {
        int c = col_sorted[j];
        float w = dinv[c];
        const float4* hp = (const float4*)&hw[(size_t)c * G_DIM];
#pragma unroll
        for (int q = 0; q < G_DIM / 4; ++q) {
            float4 v = hp[q];
            s[q * 4 + 0] = fmaf(w, v.x, s[q * 4 + 0]);
            s[q * 4 + 1] = fmaf(w, v.y, s[q * 4 + 1]);
            s[q * 4 + 2] = fmaf(w, v.z, s[q * 4 + 2]);
            s[q * 4 + 3] = fmaf(w, v.w, s[q * 4 + 3]);
        }
    }

    float di = dinv[n];
    float sn = di * di;
    const float4* selfp = (const float4*)&hw[(size_t)n * G_DIM];

    float xo[G_DIM];
#pragma unroll
    for (int q = 0; q < G_DIM / 4; ++q) {
        float4 v = selfp[q];
        xo[q * 4 + 0] = fmaxf(fmaf(di, s[q * 4 + 0], fmaf(sn, v.x, bias[q * 4 + 0])), 0.0f);
        xo[q * 4 + 1] = fmaxf(fmaf(di, s[q * 4 + 1], fmaf(sn, v.y, bias[q * 4 + 1])), 0.0f);
        xo[q * 4 + 2] = fmaxf(fmaf(di, s[q * 4 + 2], fmaf(sn, v.z, bias[q * 4 + 2])), 0.0f);
        xo[q * 4 + 3] = fmaxf(fmaf(di, s[q * 4 + 3], fmaf(sn, v.w, bias[q * 4 + 3])), 0.0f);
    }

    float4* op = (float4*)&outbuf[(size_t)n * G_DIM];
    if (DO_MATMUL) {
#pragma unroll
        for (int q = 0; q < G_DIM / 4; ++q) {
            float4 v;
            float* vv = &v.x;
#pragma unroll
            for (int u = 0; u < 4; ++u) {
                int g2 = q * 4 + u;
                float a = 0.0f;
#pragma unroll
                for (int g = 0; g < G_DIM; ++g) a = fmaf(xo[g], w2[g * G_DIM + g2], a);
                vv[u] = a;
            }
            op[q] = v;
        }
    } else {
#pragma unroll
        for (int q = 0; q < G_DIM / 4; ++q)
            op[q] = make_float4(xo[q * 4 + 0], xo[q * 4 + 1], xo[q * 4 + 2], xo[q * 4 + 3]);
    }
}

// ---------------------------------------------------------------------------
// 7) Pool: thread (graph, ch) sums x3 over the graph's node range (coalesced)
// ---------------------------------------------------------------------------
__global__ __launch_bounds__(256) void pool_kernel(
    const float* __restrict__ x3, const int* __restrict__ gptr,
    float* __restrict__ pooled)
{
    int tid = blockIdx.x * 256 + threadIdx.x;
    if (tid >= NGRAPH * G_DIM) return;
    int g = tid >> 5;          // /G_DIM
    int ch = tid & (G_DIM - 1);
    int n0 = gptr[g], n1 = gptr[g + 1];
    float a = 0.0f;
    for (int n = n0; n < n1; ++n) a += x3[(size_t)n * G_DIM + ch];
    pooled[tid] = a;
}

// ---------------------------------------------------------------------------
// 8) Head: out = (pooled @ d1_w + d1_b) @ d2_w + d2_b
// ---------------------------------------------------------------------------
__global__ __launch_bounds__(256) void head_kernel(
    const float* __restrict__ pooled,
    const float* __restrict__ d1w, const float* __restrict__ d1b,
    const float* __restrict__ d2w, const float* __restrict__ d2b,
    float* __restrict__ out)
{
    int i = blockIdx.x * 256 + threadIdx.x;
    if (i >= NGRAPH) return;

    float p[G_DIM];
#pragma unroll
    for (int g = 0; g < G_DIM; ++g) p[g] = pooled[i * G_DIM + g];

    float acc = d2b[0];
#pragma unroll
    for (int j = 0; j < D1_DIM; ++j) {
        float t = d1b[j];
#pragma unroll
        for (int g = 0; g < G_DIM; ++g) t = fmaf(p[g], d1w[g * D1_DIM + j], t);
        acc = fmaf(t, d2w[j], acc);
    }
    out[i] = acc;
}

// ---------------------------------------------------------------------------
extern "C" void kernel_launch(void* const* d_in, const int* in_sizes, int n_in,
                              void* d_out, int out_size, void* d_ws, size_t ws_size,
                              hipStream_t stream)
{
    const float* x    = (const float*)d_in[0];
    const float* e    = (const float*)d_in[1];
    const int*   ei   = (const int*)d_in[2];
    const int*   seg  = (const int*)d_in[3];
    const float* w1   = (const float*)d_in[4];
    const float* b1   = (const float*)d_in[5];
    const float* w2   = (const float*)d_in[6];
    const float* b2   = (const float*)d_in[7];
    const float* w3   = (const float*)d_in[8];
    const float* b3   = (const float*)d_in[9];
    const float* root = (const float*)d_in[10];
    const float* eb   = (const float*)d_in[11];
    const float* g1w  = (const float*)d_in[12];
    const float* g1b  = (const float*)d_in[13];
    const float* g2w  = (const float*)d_in[14];
    const float* g2b  = (const float*)d_in[15];
    const float* d1w  = (const float*)d_in[16];
    const float* d1b  = (const float*)d_in[17];
    const float* d2w  = (const float*)d_in[18];
    const float* d2b  = (const float*)d_in[19];

    const int N = in_sizes[3];            // 50000
    const int E = in_sizes[1] / S_DIM;    // 800000
    float* out = (float*)d_out;

    // Workspace layout (4-byte units, each region 16B-aligned).
    char* ws = (char*)d_ws;
    size_t off = 0;
    auto alloc = [&](size_t elems) -> char* {
        char* p = ws + off;
        off += ((elems * 4 + 15) & ~(size_t)15);
        return p;
    };
    int*   deg        = (int*)  alloc(N);            // zeroed
    int*   cnt        = (int*)  alloc(N);            // zeroed (contiguous with deg)
    int*   rowptr     = (int*)  alloc(N + 1);
    int*   gptr       = (int*)  alloc(NGRAPH + 1);
    float* dinv       = (float*)alloc(N);
    int*   col_sorted = (int*)  alloc(E);
    float* hw1        = (float*)alloc((size_t)N * G_DIM);
    float* hw2        = (float*)alloc((size_t)N * G_DIM);
    float* x3         = (float*)alloc((size_t)N * G_DIM);
    float* pooled     = (float*)alloc((size_t)NGRAPH * G_DIM);
    float* msg_sorted = (float*)alloc((size_t)E * N_OUTC);
    (void)ws_size;

    // zero deg + cnt (first two regions, contiguous)
    hipMemsetAsync(d_ws, 0, 2 * ((size_t)N * 4 + 15 & ~(size_t)15), stream);

    int ebl = (E + 255) / 256;
    int nbl = (N + 255) / 256;

    hist_kernel<<<ebl, 256, 0, stream>>>(ei, E, deg);
    scan_kernel<<<1, 1024, 0, stream>>>(deg, N, E, rowptr, dinv);
    gptr_kernel<<<(NGRAPH + 256) / 256, 256, 0, stream>>>(seg, N, gptr);
    ecc_edge_kernel<<<ebl, 256, 0, stream>>>(e, x, ei, E, w1, b1, w2, b2, w3, b3,
                                             rowptr, cnt, msg_sorted, col_sorted);
    node1_kernel<<<nbl, 256, 0, stream>>>(msg_sorted, rowptr, x, N, root, eb, g1w, hw1);
    gcn_gather_kernel<true><<<nbl, 256, 0, stream>>>(hw1, rowptr, col_sorted, dinv, N,
                                                     g1b, g2w, hw2);
    gcn_gather_kernel<false><<<nbl, 256, 0, stream>>>(hw2, rowptr, col_sorted, dinv, N,
                                                      g2b, nullptr, x3);
    pool_kernel<<<(NGRAPH * G_DIM + 255) / 256, 256, 0, stream>>>(x3, gptr, pooled);
    head_kernel<<<(NGRAPH + 255) / 256, 256, 0, stream>>>(pooled, d1w, d1b, d2w, d2b, out);
}

// Round 3
// 447.933 us; speedup vs baseline: 8.5130x; 1.0959x over previous
//
#include <hip/hip_runtime.h>

// Model dims (fixed by the reference)
#define S_DIM   6
#define H_DIM   20
#define F_INN   8
#define N_OUTC  20
#define G_DIM   32
#define D1_DIM  16
#define NGRAPH  512

// ---------------------------------------------------------------------------
// 1) Degree histogram over rows (int atomics only)
// ---------------------------------------------------------------------------
__global__ __launch_bounds__(256) void hist_kernel(
    const int* __restrict__ ei, int E, int* __restrict__ deg)
{
    int i = blockIdx.x * 256 + threadIdx.x;
    if (i >= E) return;
    atomicAdd(&deg[ei[i]], 1);
}

// ---------------------------------------------------------------------------
// 2a) Per-block sums of deg (coalesced)
// ---------------------------------------------------------------------------
__global__ __launch_bounds__(256) void scanA_kernel(
    const int* __restrict__ deg, int N, int* __restrict__ bsum)
{
    int i = blockIdx.x * 256 + threadIdx.x;
    int v = (i < N) ? deg[i] : 0;
    // wave reduce
#pragma unroll
    for (int d = 1; d < 64; d <<= 1) v += __shfl_down(v, d, 64);
    __shared__ int ws[4];
    int wid = threadIdx.x >> 6;
    if ((threadIdx.x & 63) == 0) ws[wid] = v;
    __syncthreads();
    if (threadIdx.x == 0) bsum[blockIdx.x] = ws[0] + ws[1] + ws[2] + ws[3];
}

// ---------------------------------------------------------------------------
// 2b) Exclusive scan of block sums (<=256 blocks) in one small block
// ---------------------------------------------------------------------------
__global__ __launch_bounds__(256) void scanB_kernel(
    const int* __restrict__ bsum, int nb, int E,
    int* __restrict__ boff, int* __restrict__ rowptr, int N)
{
    int t = threadIdx.x;
    int v = (t < nb) ? bsum[t] : 0;
    int orig = v;
    // wave inclusive scan
#pragma unroll
    for (int d = 1; d < 64; d <<= 1) {
        int u = __shfl_up(v, d, 64);
        if ((t & 63) >= d) v += u;
    }
    __shared__ int ws[4];
    int wid = t >> 6;
    if ((t & 63) == 63) ws[wid] = v;
    __syncthreads();
    int woff = 0;
    for (int w = 0; w < wid; ++w) woff += ws[w];
    if (t < nb) boff[t] = woff + v - orig;   // exclusive
    if (t == 0) rowptr[N] = E;
}

// ---------------------------------------------------------------------------
// 2c) Apply: block-local exclusive scan + block offset -> rowptr; dinv
// ---------------------------------------------------------------------------
__global__ __launch_bounds__(256) void scanC_kernel(
    const int* __restrict__ deg, int N, const int* __restrict__ boff,
    int* __restrict__ rowptr, float* __restrict__ dinv)
{
    int i = blockIdx.x * 256 + threadIdx.x;
    int t = threadIdx.x;
    int d0 = (i < N) ? deg[i] : 0;
    int v = d0;
#pragma unroll
    for (int d = 1; d < 64; d <<= 1) {
        int u = __shfl_up(v, d, 64);
        if ((t & 63) >= d) v += u;
    }
    __shared__ int ws[4];
    int wid = t >> 6;
    if ((t & 63) == 63) ws[wid] = v;
    __syncthreads();
    int woff = 0;
    for (int w = 0; w < wid; ++w) woff += ws[w];
    if (i < N) {
        rowptr[i] = boff[blockIdx.x] + woff + v - d0;  // exclusive prefix
        dinv[i] = rsqrtf((float)d0 + 1.0f);
    }
}

// ---------------------------------------------------------------------------
// 3) Graph boundary pointers via binary search on sorted seg
// ---------------------------------------------------------------------------
__global__ __launch_bounds__(256) void gptr_kernel(
    const int* __restrict__ seg, int N, int* __restrict__ gptr)
{
    int g = blockIdx.x * 256 + threadIdx.x;
    if (g > NGRAPH) return;
    int lo = 0, hi = N;
    while (lo < hi) {
        int m = (lo + hi) >> 1;
        if (seg[m] < g) lo = m + 1; else hi = m;
    }
    gptr[g] = lo;
}

// ---------------------------------------------------------------------------
// 4) Slot assignment: edge -> CSR slot (1 int atomic/edge, 8B scattered writes)
// ---------------------------------------------------------------------------
__global__ __launch_bounds__(256) void slot_kernel(
    const int* __restrict__ ei, int E, const int* __restrict__ rowptr,
    int* __restrict__ cnt, int* __restrict__ eid_at_slot,
    int* __restrict__ col_sorted)
{
    int i = blockIdx.x * 256 + threadIdx.x;
    if (i >= E) return;
    int r = ei[i];
    int p = rowptr[r] + atomicAdd(&cnt[r], 1);
    eid_at_slot[p] = i;
    col_sorted[p] = ei[E + i];
}

// ---------------------------------------------------------------------------
// 5) Fused ECC edge kernel in CSR order: per-edge MLP + einsum with x[col];
//    coalesced msg write. No atomics.
// ---------------------------------------------------------------------------
__global__ __launch_bounds__(256) void ecc_edge_kernel(
    const float* __restrict__ e, const float* __restrict__ x,
    const int* __restrict__ eid_at_slot, const int* __restrict__ col_sorted,
    int E,
    const float* __restrict__ w1, const float* __restrict__ b1,
    const float* __restrict__ w2, const float* __restrict__ b2,
    const float* __restrict__ w3, const float* __restrict__ b3,
    float* __restrict__ msg_sorted)
{
    int j = blockIdx.x * 256 + threadIdx.x;
    if (j >= E) return;
    int i = eid_at_slot[j];
    int c = col_sorted[j];

    float ef[S_DIM];
#pragma unroll
    for (int s = 0; s < S_DIM; ++s) ef[s] = e[(size_t)i * S_DIM + s];

    // h1 = relu(e @ w1 + b1)
    float h1[H_DIM];
#pragma unroll
    for (int jj = 0; jj < H_DIM; ++jj) {
        float a = b1[jj];
#pragma unroll
        for (int s = 0; s < S_DIM; ++s) a = fmaf(ef[s], w1[s * H_DIM + jj], a);
        h1[jj] = fmaxf(a, 0.0f);
    }

    // h2 = relu(h1 @ w2 + b2)
    float h2[H_DIM];
#pragma unroll
    for (int jj = 0; jj < H_DIM; ++jj) {
        float a = b2[jj];
#pragma unroll
        for (int k = 0; k < H_DIM; ++k) a = fmaf(h1[k], w2[k * H_DIM + jj], a);
        h2[jj] = fmaxf(a, 0.0f);
    }

    // x[col] as two float4
    const float4* xp = (const float4*)&x[(size_t)c * F_INN];
    float4 xa = xp[0], xb = xp[1];
    float xf[F_INN] = {xa.x, xa.y, xa.z, xa.w, xb.x, xb.y, xb.z, xb.w};

    // msg[o] = sum_f xf[f] * (b3[f,o] + sum_k h2[k]*w3[k, f*N_OUT+o])
    float msg[N_OUTC];
#pragma unroll
    for (int o = 0; o < N_OUTC; ++o) msg[o] = 0.0f;

    for (int f = 0; f < F_INN; ++f) {           // rolled: f stays wave-uniform
        float xv = xf[f];
#pragma unroll
        for (int o = 0; o < N_OUTC; ++o) {
            float w = b3[f * N_OUTC + o];
#pragma unroll
            for (int k = 0; k < H_DIM; ++k)
                w = fmaf(h2[k], w3[k * (F_INN * N_OUTC) + f * N_OUTC + o], w);
            msg[o] = fmaf(xv, w, msg[o]);
        }
    }

    float4* mp = (float4*)&msg_sorted[(size_t)j * N_OUTC];
    mp[0] = make_float4(msg[0],  msg[1],  msg[2],  msg[3]);
    mp[1] = make_float4(msg[4],  msg[5],  msg[6],  msg[7]);
    mp[2] = make_float4(msg[8],  msg[9],  msg[10], msg[11]);
    mp[3] = make_float4(msg[12], msg[13], msg[14], msg[15]);
    mp[4] = make_float4(msg[16], msg[17], msg[18], msg[19]);
}

// ---------------------------------------------------------------------------
// 6a) CSR segment-sum of msg_sorted: thread = (node, float4-lane q of 5)
// ---------------------------------------------------------------------------
__global__ __launch_bounds__(256) void agg_kernel(
    const float* __restrict__ msg_sorted, const int* __restrict__ rowptr,
    int N, float* __restrict__ agg)
{
    int tid = blockIdx.x * 256 + threadIdx.x;
    if (tid >= N * 5) return;
    int n = tid / 5;
    int q = tid - n * 5;
    int j0 = rowptr[n], j1 = rowptr[n + 1];
    const float4* mp = (const float4*)msg_sorted;
    float4 a = make_float4(0.f, 0.f, 0.f, 0.f);
    for (int j = j0; j < j1; ++j) {
        float4 v = mp[(size_t)j * 5 + q];
        a.x += v.x; a.y += v.y; a.z += v.z; a.w += v.w;
    }
    ((float4*)agg)[(size_t)n * 5 + q] = a;
}

// ---------------------------------------------------------------------------
// 6b) Node transform: x1 = relu(agg + x@root + b); hw1 = x1 @ gcn1_w
// ---------------------------------------------------------------------------
__global__ __launch_bounds__(256) void node1_kernel(
    const float* __restrict__ agg, const float* __restrict__ x, int N,
    const float* __restrict__ root, const float* __restrict__ eb,
    const float* __restrict__ g1w,
    float* __restrict__ hw1)
{
    int n = blockIdx.x * 256 + threadIdx.x;
    if (n >= N) return;

    const float4* xp = (const float4*)&x[(size_t)n * F_INN];
    float4 xa = xp[0], xb = xp[1];
    float xf[F_INN] = {xa.x, xa.y, xa.z, xa.w, xb.x, xb.y, xb.z, xb.w};

    float x1[N_OUTC];
#pragma unroll
    for (int o = 0; o < N_OUTC; ++o) {
        float a = agg[(size_t)n * N_OUTC + o] + eb[o];
#pragma unroll
        for (int f = 0; f < F_INN; ++f) a = fmaf(xf[f], root[f * N_OUTC + o], a);
        x1[o] = fmaxf(a, 0.0f);
    }

    float4* hp = (float4*)&hw1[(size_t)n * G_DIM];
#pragma unroll
    for (int q = 0; q < G_DIM / 4; ++q) {
        float4 v;
        float* vv = &v.x;
#pragma unroll
        for (int u = 0; u < 4; ++u) {
            int g = q * 4 + u;
            float a = 0.0f;
#pragma unroll
            for (int o = 0; o < N_OUTC; ++o) a = fmaf(x1[o], g1w[o * G_DIM + g], a);
            vv[u] = a;
        }
        hp[q] = v;
    }
}

// ---------------------------------------------------------------------------
// 7) GCN layer (gather): s = sum_j dinv[col_j]*hw[col_j];
//    x' = relu(dinv[n]*s + dinv[n]^2*hw[n] + b); out = x' @ W2 (or x' itself)
// ---------------------------------------------------------------------------
template<bool DO_MATMUL>
__global__ __launch_bounds__(256) void gcn_gather_kernel(
    const float* __restrict__ hw, const int* __restrict__ rowptr,
    const int* __restrict__ col_sorted, const float* __restrict__ dinv, int N,
    const float* __restrict__ bias, const float* __restrict__ w2,
    float* __restrict__ outbuf)
{
    int n = blockIdx.x * 256 + threadIdx.x;
    if (n >= N) return;
    int j0 = rowptr[n], j1 = rowptr[n + 1];

    float s[G_DIM];
#pragma unroll
    for (int g = 0; g < G_DIM; ++g) s[g] = 0.0f;

    for (int j = j0; j < j1; ++j) {
        int c = col_sorted[j];
        float w = dinv[c];
        const float4* hp = (const float4*)&hw[(size_t)c * G_DIM];
#pragma unroll
        for (int q = 0; q < G_DIM / 4; ++q) {
            float4 v = hp[q];
            s[q * 4 + 0] = fmaf(w, v.x, s[q * 4 + 0]);
            s[q * 4 + 1] = fmaf(w, v.y, s[q * 4 + 1]);
            s[q * 4 + 2] = fmaf(w, v.z, s[q * 4 + 2]);
            s[q * 4 + 3] = fmaf(w, v.w, s[q * 4 + 3]);
        }
    }

    float di = dinv[n];
    float sn = di * di;
    const float4* selfp = (const float4*)&hw[(size_t)n * G_DIM];

    float xo[G_DIM];
#pragma unroll
    for (int q = 0; q < G_DIM / 4; ++q) {
        float4 v = selfp[q];
        xo[q * 4 + 0] = fmaxf(fmaf(di, s[q * 4 + 0], fmaf(sn, v.x, bias[q * 4 + 0])), 0.0f);
        xo[q * 4 + 1] = fmaxf(fmaf(di, s[q * 4 + 1], fmaf(sn, v.y, bias[q * 4 + 1])), 0.0f);
        xo[q * 4 + 2] = fmaxf(fmaf(di, s[q * 4 + 2], fmaf(sn, v.z, bias[q * 4 + 2])), 0.0f);
        xo[q * 4 + 3] = fmaxf(fmaf(di, s[q * 4 + 3], fmaf(sn, v.w, bias[q * 4 + 3])), 0.0f);
    }

    float4* op = (float4*)&outbuf[(size_t)n * G_DIM];
    if (DO_MATMUL) {
#pragma unroll
        for (int q = 0; q < G_DIM / 4; ++q) {
            float4 v;
            float* vv = &v.x;
#pragma unroll
            for (int u = 0; u < 4; ++u) {
                int g2 = q * 4 + u;
                float a = 0.0f;
#pragma unroll
                for (int g = 0; g < G_DIM; ++g) a = fmaf(xo[g], w2[g * G_DIM + g2], a);
                vv[u] = a;
            }
            op[q] = v;
        }
    } else {
#pragma unroll
        for (int q = 0; q < G_DIM / 4; ++q)
            op[q] = make_float4(xo[q * 4 + 0], xo[q * 4 + 1], xo[q * 4 + 2], xo[q * 4 + 3]);
    }
}

// ---------------------------------------------------------------------------
// 8) Pool: thread (graph, ch) sums x3 over the graph's node range (coalesced)
// ---------------------------------------------------------------------------
__global__ __launch_bounds__(256) void pool_kernel(
    const float* __restrict__ x3, const int* __restrict__ gptr,
    float* __restrict__ pooled)
{
    int tid = blockIdx.x * 256 + threadIdx.x;
    if (tid >= NGRAPH * G_DIM) return;
    int g = tid >> 5;          // /G_DIM
    int ch = tid & (G_DIM - 1);
    int n0 = gptr[g], n1 = gptr[g + 1];
    float a = 0.0f;
    for (int n = n0; n < n1; ++n) a += x3[(size_t)n * G_DIM + ch];
    pooled[tid] = a;
}

// ---------------------------------------------------------------------------
// 9) Head: out = (pooled @ d1_w + d1_b) @ d2_w + d2_b
// ---------------------------------------------------------------------------
__global__ __launch_bounds__(256) void head_kernel(
    const float* __restrict__ pooled,
    const float* __restrict__ d1w, const float* __restrict__ d1b,
    const float* __restrict__ d2w, const float* __restrict__ d2b,
    float* __restrict__ out)
{
    int i = blockIdx.x * 256 + threadIdx.x;
    if (i >= NGRAPH) return;

    float p[G_DIM];
#pragma unroll
    for (int g = 0; g < G_DIM; ++g) p[g] = pooled[i * G_DIM + g];

    float acc = d2b[0];
#pragma unroll
    for (int j = 0; j < D1_DIM; ++j) {
        float t = d1b[j];
#pragma unroll
        for (int g = 0; g < G_DIM; ++g) t = fmaf(p[g], d1w[g * D1_DIM + j], t);
        acc = fmaf(t, d2w[j], acc);
    }
    out[i] = acc;
}

// ---------------------------------------------------------------------------
extern "C" void kernel_launch(void* const* d_in, const int* in_sizes, int n_in,
                              void* d_out, int out_size, void* d_ws, size_t ws_size,
                              hipStream_t stream)
{
    const float* x    = (const float*)d_in[0];
    const float* e    = (const float*)d_in[1];
    const int*   ei   = (const int*)d_in[2];
    const int*   seg  = (const int*)d_in[3];
    const float* w1   = (const float*)d_in[4];
    const float* b1   = (const float*)d_in[5];
    const float* w2   = (const float*)d_in[6];
    const float* b2   = (const float*)d_in[7];
    const float* w3   = (const float*)d_in[8];
    const float* b3   = (const float*)d_in[9];
    const float* root = (const float*)d_in[10];
    const float* eb   = (const float*)d_in[11];
    const float* g1w  = (const float*)d_in[12];
    const float* g1b  = (const float*)d_in[13];
    const float* g2w  = (const float*)d_in[14];
    const float* g2b  = (const float*)d_in[15];
    const float* d1w  = (const float*)d_in[16];
    const float* d1b  = (const float*)d_in[17];
    const float* d2w  = (const float*)d_in[18];
    const float* d2b  = (const float*)d_in[19];

    const int N = in_sizes[3];            // 50000
    const int E = in_sizes[1] / S_DIM;    // 800000
    float* out = (float*)d_out;

    const int nbl = (N + 255) / 256;      // 196 blocks (<= 256 for scanB)
    const int ebl = (E + 255) / 256;

    // Workspace layout (each region 16B-aligned).
    char* ws = (char*)d_ws;
    size_t off = 0;
    auto alloc = [&](size_t elems) -> char* {
        char* p = ws + off;
        off += ((elems * 4 + 15) & ~(size_t)15);
        return p;
    };
    int*   deg        = (int*)  alloc(N);            // zeroed
    int*   cnt        = (int*)  alloc(N);            // zeroed (contiguous with deg)
    int*   rowptr     = (int*)  alloc(N + 1);
    int*   bsum       = (int*)  alloc(nbl);
    int*   boff       = (int*)  alloc(nbl);
    int*   gptr       = (int*)  alloc(NGRAPH + 1);
    float* dinv       = (float*)alloc(N);
    int*   eid_at_slot= (int*)  alloc(E);
    int*   col_sorted = (int*)  alloc(E);
    float* agg        = (float*)alloc((size_t)N * N_OUTC);
    float* hw1        = (float*)alloc((size_t)N * G_DIM);
    float* hw2        = (float*)alloc((size_t)N * G_DIM);
    float* x3         = (float*)alloc((size_t)N * G_DIM);
    float* pooled     = (float*)alloc((size_t)NGRAPH * G_DIM);
    float* msg_sorted = (float*)alloc((size_t)E * N_OUTC);
    (void)ws_size;

    // zero deg + cnt (first two regions, contiguous, each 16B-multiple)
    hipMemsetAsync(d_ws, 0, 2 * (((size_t)N * 4 + 15) & ~(size_t)15), stream);

    hist_kernel<<<ebl, 256, 0, stream>>>(ei, E, deg);
    scanA_kernel<<<nbl, 256, 0, stream>>>(deg, N, bsum);
    scanB_kernel<<<1, 256, 0, stream>>>(bsum, nbl, E, boff, rowptr, N);
    scanC_kernel<<<nbl, 256, 0, stream>>>(deg, N, boff, rowptr, dinv);
    gptr_kernel<<<(NGRAPH + 256) / 256, 256, 0, stream>>>(seg, N, gptr);
    slot_kernel<<<ebl, 256, 0, stream>>>(ei, E, rowptr, cnt, eid_at_slot, col_sorted);
    ecc_edge_kernel<<<ebl, 256, 0, stream>>>(e, x, eid_at_slot, col_sorted, E,
                                             w1, b1, w2, b2, w3, b3, msg_sorted);
    agg_kernel<<<(N * 5 + 255) / 256, 256, 0, stream>>>(msg_sorted, rowptr, N, agg);
    node1_kernel<<<nbl, 256, 0, stream>>>(agg, x, N, root, eb, g1w, hw1);
    gcn_gather_kernel<true><<<nbl, 256, 0, stream>>>(hw1, rowptr, col_sorted, dinv, N,
                                                     g1b, g2w, hw2);
    gcn_gather_kernel<false><<<nbl, 256, 0, stream>>>(hw2, rowptr, col_sorted, dinv, N,
                                                      g2b, nullptr, x3);
    pool_kernel<<<(NGRAPH * G_DIM + 255) / 256, 256, 0, stream>>>(x3, gptr, pooled);
    head_kernel<<<(NGRAPH + 255) / 256, 256, 0, stream>>>(pooled, d1w, d1b, d2w, d2b, out);
}

// Round 4
// 396.054 us; speedup vs baseline: 9.6282x; 1.1310x over previous
//
#include <hip/hip_runtime.h>

// Model dims (fixed by the reference)
#define S_DIM   6
#define H_DIM   20
#define F_INN   8
#define N_OUTC  20
#define G_DIM   32
#define D1_DIM  16
#define NGRAPH  512

// ---------------------------------------------------------------------------
// 1) Degree histogram over rows (int atomics only)
// ---------------------------------------------------------------------------
__global__ __launch_bounds__(256) void hist_kernel(
    const int* __restrict__ ei, int E, int* __restrict__ deg)
{
    int i = blockIdx.x * 256 + threadIdx.x;
    if (i >= E) return;
    atomicAdd(&deg[ei[i]], 1);
}

// ---------------------------------------------------------------------------
// 2a) Per-block sums of deg (coalesced)
// ---------------------------------------------------------------------------
__global__ __launch_bounds__(256) void scanA_kernel(
    const int* __restrict__ deg, int N, int* __restrict__ bsum)
{
    int i = blockIdx.x * 256 + threadIdx.x;
    int v = (i < N) ? deg[i] : 0;
#pragma unroll
    for (int d = 1; d < 64; d <<= 1) v += __shfl_down(v, d, 64);
    __shared__ int ws[4];
    int wid = threadIdx.x >> 6;
    if ((threadIdx.x & 63) == 0) ws[wid] = v;
    __syncthreads();
    if (threadIdx.x == 0) bsum[blockIdx.x] = ws[0] + ws[1] + ws[2] + ws[3];
}

// ---------------------------------------------------------------------------
// 2b) Exclusive scan of block sums (<=256 blocks) in one small block
// ---------------------------------------------------------------------------
__global__ __launch_bounds__(256) void scanB_kernel(
    const int* __restrict__ bsum, int nb, int E,
    int* __restrict__ boff, int* __restrict__ rowptr, int N)
{
    int t = threadIdx.x;
    int v = (t < nb) ? bsum[t] : 0;
    int orig = v;
#pragma unroll
    for (int d = 1; d < 64; d <<= 1) {
        int u = __shfl_up(v, d, 64);
        if ((t & 63) >= d) v += u;
    }
    __shared__ int ws[4];
    int wid = t >> 6;
    if ((t & 63) == 63) ws[wid] = v;
    __syncthreads();
    int woff = 0;
    for (int w = 0; w < wid; ++w) woff += ws[w];
    if (t < nb) boff[t] = woff + v - orig;   // exclusive
    if (t == 0) rowptr[N] = E;
}

// ---------------------------------------------------------------------------
// 2c) Apply: block-local exclusive scan + block offset -> rowptr; dinv
// ---------------------------------------------------------------------------
__global__ __launch_bounds__(256) void scanC_kernel(
    const int* __restrict__ deg, int N, const int* __restrict__ boff,
    int* __restrict__ rowptr, float* __restrict__ dinv)
{
    int i = blockIdx.x * 256 + threadIdx.x;
    int t = threadIdx.x;
    int d0 = (i < N) ? deg[i] : 0;
    int v = d0;
#pragma unroll
    for (int d = 1; d < 64; d <<= 1) {
        int u = __shfl_up(v, d, 64);
        if ((t & 63) >= d) v += u;
    }
    __shared__ int ws[4];
    int wid = t >> 6;
    if ((t & 63) == 63) ws[wid] = v;
    __syncthreads();
    int woff = 0;
    for (int w = 0; w < wid; ++w) woff += ws[w];
    if (i < N) {
        rowptr[i] = boff[blockIdx.x] + woff + v - d0;  // exclusive prefix
        dinv[i] = rsqrtf((float)d0 + 1.0f);
    }
}

// ---------------------------------------------------------------------------
// 3) Slot assignment: edge -> CSR slot (1 int atomic/edge)
// ---------------------------------------------------------------------------
__global__ __launch_bounds__(256) void slot_kernel(
    const int* __restrict__ ei, int E, const int* __restrict__ rowptr,
    int* __restrict__ cnt, int* __restrict__ eid_at_slot,
    int* __restrict__ col_sorted)
{
    int i = blockIdx.x * 256 + threadIdx.x;
    if (i >= E) return;
    int r = ei[i];
    int p = rowptr[r] + atomicAdd(&cnt[r], 1);
    eid_at_slot[p] = i;
    col_sorted[p] = ei[E + i];
}

// ---------------------------------------------------------------------------
// 4) Fused ECC edge kernel in CSR order; msg stored CHUNK-MAJOR [5][E][4]
//    so the agg kernel streams sequentially. Coalesced writes, no atomics.
// ---------------------------------------------------------------------------
__global__ __launch_bounds__(256) void ecc_edge_kernel(
    const float* __restrict__ e, const float* __restrict__ x,
    const int* __restrict__ eid_at_slot, const int* __restrict__ col_sorted,
    int E,
    const float* __restrict__ w1, const float* __restrict__ b1,
    const float* __restrict__ w2, const float* __restrict__ b2,
    const float* __restrict__ w3, const float* __restrict__ b3,
    float* __restrict__ msg_sorted)
{
    int j = blockIdx.x * 256 + threadIdx.x;
    if (j >= E) return;
    int i = eid_at_slot[j];
    int c = col_sorted[j];

    float ef[S_DIM];
#pragma unroll
    for (int s = 0; s < S_DIM; ++s) ef[s] = e[(size_t)i * S_DIM + s];

    float h1[H_DIM];
#pragma unroll
    for (int jj = 0; jj < H_DIM; ++jj) {
        float a = b1[jj];
#pragma unroll
        for (int s = 0; s < S_DIM; ++s) a = fmaf(ef[s], w1[s * H_DIM + jj], a);
        h1[jj] = fmaxf(a, 0.0f);
    }

    float h2[H_DIM];
#pragma unroll
    for (int jj = 0; jj < H_DIM; ++jj) {
        float a = b2[jj];
#pragma unroll
        for (int k = 0; k < H_DIM; ++k) a = fmaf(h1[k], w2[k * H_DIM + jj], a);
        h2[jj] = fmaxf(a, 0.0f);
    }

    const float4* xp = (const float4*)&x[(size_t)c * F_INN];
    float4 xa = xp[0], xb = xp[1];
    float xf[F_INN] = {xa.x, xa.y, xa.z, xa.w, xb.x, xb.y, xb.z, xb.w};

    float msg[N_OUTC];
#pragma unroll
    for (int o = 0; o < N_OUTC; ++o) msg[o] = 0.0f;

    for (int f = 0; f < F_INN; ++f) {           // rolled: f stays wave-uniform
        float xv = xf[f];
#pragma unroll
        for (int o = 0; o < N_OUTC; ++o) {
            float w = b3[f * N_OUTC + o];
#pragma unroll
            for (int k = 0; k < H_DIM; ++k)
                w = fmaf(h2[k], w3[k * (F_INN * N_OUTC) + f * N_OUTC + o], w);
            msg[o] = fmaf(xv, w, msg[o]);
        }
    }

    float4* mp = (float4*)msg_sorted;
    size_t jj = (size_t)j;
    mp[0 * (size_t)E + jj] = make_float4(msg[0],  msg[1],  msg[2],  msg[3]);
    mp[1 * (size_t)E + jj] = make_float4(msg[4],  msg[5],  msg[6],  msg[7]);
    mp[2 * (size_t)E + jj] = make_float4(msg[8],  msg[9],  msg[10], msg[11]);
    mp[3 * (size_t)E + jj] = make_float4(msg[12], msg[13], msg[14], msg[15]);
    mp[4 * (size_t)E + jj] = make_float4(msg[16], msg[17], msg[18], msg[19]);
}

// ---------------------------------------------------------------------------
// 5) CSR segment-sum of msg (chunk-major): block = 64 nodes x 5 chunks.
//    Each thread streams a fully-sequential float4 run.
// ---------------------------------------------------------------------------
__global__ __launch_bounds__(320) void agg_kernel(
    const float* __restrict__ msg_sorted, const int* __restrict__ rowptr,
    int N, int E, float* __restrict__ agg)
{
    int t = threadIdx.x;
    int nl = t / 5;
    int q = t - nl * 5;
    int n = blockIdx.x * 64 + nl;
    if (n >= N) return;
    int j0 = rowptr[n], j1 = rowptr[n + 1];
    const float4* mp = (const float4*)msg_sorted + (size_t)q * E;
    float4 a = make_float4(0.f, 0.f, 0.f, 0.f);
    for (int j = j0; j < j1; ++j) {
        float4 v = mp[j];
        a.x += v.x; a.y += v.y; a.z += v.z; a.w += v.w;
    }
    ((float4*)(agg + (size_t)n * N_OUTC))[q] = a;
}

// ---------------------------------------------------------------------------
// 6) Node transform: x1 = relu(agg + x@root + b); hw1 = x1 @ gcn1_w
// ---------------------------------------------------------------------------
__global__ __launch_bounds__(256) void node1_kernel(
    const float* __restrict__ agg, const float* __restrict__ x, int N,
    const float* __restrict__ root, const float* __restrict__ eb,
    const float* __restrict__ g1w,
    float* __restrict__ hw1)
{
    int n = blockIdx.x * 256 + threadIdx.x;
    if (n >= N) return;

    const float4* xp = (const float4*)&x[(size_t)n * F_INN];
    float4 xa = xp[0], xb = xp[1];
    float xf[F_INN] = {xa.x, xa.y, xa.z, xa.w, xb.x, xb.y, xb.z, xb.w};

    float x1[N_OUTC];
#pragma unroll
    for (int o = 0; o < N_OUTC; ++o) {
        float a = agg[(size_t)n * N_OUTC + o] + eb[o];
#pragma unroll
        for (int f = 0; f < F_INN; ++f) a = fmaf(xf[f], root[f * N_OUTC + o], a);
        x1[o] = fmaxf(a, 0.0f);
    }

    float4* hp = (float4*)&hw1[(size_t)n * G_DIM];
#pragma unroll
    for (int q = 0; q < G_DIM / 4; ++q) {
        float4 v;
        float* vv = &v.x;
#pragma unroll
        for (int u = 0; u < 4; ++u) {
            int g = q * 4 + u;
            float a = 0.0f;
#pragma unroll
            for (int o = 0; o < N_OUTC; ++o) a = fmaf(x1[o], g1w[o * G_DIM + g], a);
            vv[u] = a;
        }
        hp[q] = v;
    }
}

// ---------------------------------------------------------------------------
// 7) GCN gather, thread = (node, float4-chunk of 8). Block = 32 nodes x 8.
//    A node's 8 threads fetch one whole 128B hw[c] line together.
//    DO_MATMUL: stage x' in LDS, fused @W2 epilogue (w2 preloaded in LDS).
// ---------------------------------------------------------------------------
template<bool DO_MATMUL>
__global__ __launch_bounds__(256) void gcn_gather_kernel(
    const float* __restrict__ hw, const int* __restrict__ rowptr,
    const int* __restrict__ col_sorted, const float* __restrict__ dinv, int N,
    const float* __restrict__ bias, const float* __restrict__ w2,
    float* __restrict__ outbuf)
{
    __shared__ float x2s[32 * 33];
    __shared__ float w2s[G_DIM * G_DIM];

    int t = threadIdx.x;
    int nl = t >> 3;
    int q = t & 7;
    int n = blockIdx.x * 32 + nl;

    if (DO_MATMUL) {
        // coalesced float4 preload of w2 (32x32)
        ((float4*)w2s)[t] = ((const float4*)w2)[t];
    }

    float4 xo = make_float4(0.f, 0.f, 0.f, 0.f);
    if (n < N) {
        int j0 = rowptr[n], j1 = rowptr[n + 1];
        float4 s = make_float4(0.f, 0.f, 0.f, 0.f);
        for (int j = j0; j < j1; ++j) {
            int c = col_sorted[j];
            float w = dinv[c];
            float4 v = *(const float4*)&hw[(size_t)c * G_DIM + q * 4];
            s.x = fmaf(w, v.x, s.x);
            s.y = fmaf(w, v.y, s.y);
            s.z = fmaf(w, v.z, s.z);
            s.w = fmaf(w, v.w, s.w);
        }
        float di = dinv[n];
        float sn = di * di;
        float4 self = *(const float4*)&hw[(size_t)n * G_DIM + q * 4];
        const float4 b4 = *(const float4*)&bias[q * 4];
        xo.x = fmaxf(fmaf(di, s.x, fmaf(sn, self.x, b4.x)), 0.0f);
        xo.y = fmaxf(fmaf(di, s.y, fmaf(sn, self.y, b4.y)), 0.0f);
        xo.z = fmaxf(fmaf(di, s.z, fmaf(sn, self.z, b4.z)), 0.0f);
        xo.w = fmaxf(fmaf(di, s.w, fmaf(sn, self.w, b4.w)), 0.0f);
    }

    if (DO_MATMUL) {
        x2s[nl * 33 + q * 4 + 0] = xo.x;
        x2s[nl * 33 + q * 4 + 1] = xo.y;
        x2s[nl * 33 + q * 4 + 2] = xo.z;
        x2s[nl * 33 + q * 4 + 3] = xo.w;
        __syncthreads();
        if (n < N) {
            float a0 = 0.f, a1 = 0.f, a2 = 0.f, a3 = 0.f;
            const float* xr = &x2s[nl * 33];
#pragma unroll
            for (int g = 0; g < G_DIM; ++g) {
                float xv = xr[g];
                a0 = fmaf(xv, w2s[g * G_DIM + q * 4 + 0], a0);
                a1 = fmaf(xv, w2s[g * G_DIM + q * 4 + 1], a1);
                a2 = fmaf(xv, w2s[g * G_DIM + q * 4 + 2], a2);
                a3 = fmaf(xv, w2s[g * G_DIM + q * 4 + 3], a3);
            }
            *(float4*)&outbuf[(size_t)n * G_DIM + q * 4] = make_float4(a0, a1, a2, a3);
        }
    } else {
        if (n < N)
            *(float4*)&outbuf[(size_t)n * G_DIM + q * 4] = xo;
    }
}

// ---------------------------------------------------------------------------
// 8) Pool: block per graph; inline binary search for node range;
//    8 slices x 32 channels, LDS reduce.
// ---------------------------------------------------------------------------
__global__ __launch_bounds__(256) void pool_kernel(
    const float* __restrict__ x3, const int* __restrict__ seg, int N,
    float* __restrict__ pooled)
{
    __shared__ float red[8][G_DIM];
    __shared__ int bounds[2];
    int g = blockIdx.x;
    int t = threadIdx.x;
    if (t < 2) {
        int target = g + t;
        int lo = 0, hi = N;
        while (lo < hi) {
            int m = (lo + hi) >> 1;
            if (seg[m] < target) lo = m + 1; else hi = m;
        }
        bounds[t] = lo;
    }
    __syncthreads();
    int n0 = bounds[0], n1 = bounds[1];
    int ch = t & (G_DIM - 1);
    int slice = t >> 5;
    float a = 0.0f;
    for (int n = n0 + slice; n < n1; n += 8)
        a += x3[(size_t)n * G_DIM + ch];
    red[slice][ch] = a;
    __syncthreads();
    if (slice == 0) {
        float s = red[0][ch];
#pragma unroll
        for (int k = 1; k < 8; ++k) s += red[k][ch];
        pooled[g * G_DIM + ch] = s;
    }
}

// ---------------------------------------------------------------------------
// 9) Head: out = (pooled @ d1_w + d1_b) @ d2_w + d2_b
// ---------------------------------------------------------------------------
__global__ __launch_bounds__(256) void head_kernel(
    const float* __restrict__ pooled,
    const float* __restrict__ d1w, const float* __restrict__ d1b,
    const float* __restrict__ d2w, const float* __restrict__ d2b,
    float* __restrict__ out)
{
    int i = blockIdx.x * 256 + threadIdx.x;
    if (i >= NGRAPH) return;

    float p[G_DIM];
#pragma unroll
    for (int g = 0; g < G_DIM; ++g) p[g] = pooled[i * G_DIM + g];

    float acc = d2b[0];
#pragma unroll
    for (int j = 0; j < D1_DIM; ++j) {
        float t = d1b[j];
#pragma unroll
        for (int g = 0; g < G_DIM; ++g) t = fmaf(p[g], d1w[g * D1_DIM + j], t);
        acc = fmaf(t, d2w[j], acc);
    }
    out[i] = acc;
}

// ---------------------------------------------------------------------------
extern "C" void kernel_launch(void* const* d_in, const int* in_sizes, int n_in,
                              void* d_out, int out_size, void* d_ws, size_t ws_size,
                              hipStream_t stream)
{
    const float* x    = (const float*)d_in[0];
    const float* e    = (const float*)d_in[1];
    const int*   ei   = (const int*)d_in[2];
    const int*   seg  = (const int*)d_in[3];
    const float* w1   = (const float*)d_in[4];
    const float* b1   = (const float*)d_in[5];
    const float* w2   = (const float*)d_in[6];
    const float* b2   = (const float*)d_in[7];
    const float* w3   = (const float*)d_in[8];
    const float* b3   = (const float*)d_in[9];
    const float* root = (const float*)d_in[10];
    const float* eb   = (const float*)d_in[11];
    const float* g1w  = (const float*)d_in[12];
    const float* g1b  = (const float*)d_in[13];
    const float* g2w  = (const float*)d_in[14];
    const float* g2b  = (const float*)d_in[15];
    const float* d1w  = (const float*)d_in[16];
    const float* d1b  = (const float*)d_in[17];
    const float* d2w  = (const float*)d_in[18];
    const float* d2b  = (const float*)d_in[19];

    const int N = in_sizes[3];            // 50000
    const int E = in_sizes[1] / S_DIM;    // 800000
    float* out = (float*)d_out;

    const int nbl = (N + 255) / 256;      // 196 blocks (<= 256 for scanB)
    const int ebl = (E + 255) / 256;

    // Workspace layout (each region 16B-aligned).
    char* ws = (char*)d_ws;
    size_t off = 0;
    auto alloc = [&](size_t elems) -> char* {
        char* p = ws + off;
        off += ((elems * 4 + 15) & ~(size_t)15);
        return p;
    };
    int*   deg        = (int*)  alloc(N);            // zeroed
    int*   cnt        = (int*)  alloc(N);            // zeroed (contiguous with deg)
    int*   rowptr     = (int*)  alloc(N + 1);
    int*   bsum       = (int*)  alloc(nbl);
    int*   boff       = (int*)  alloc(nbl);
    float* dinv       = (float*)alloc(N);
    int*   eid_at_slot= (int*)  alloc(E);
    int*   col_sorted = (int*)  alloc(E);
    float* agg        = (float*)alloc((size_t)N * N_OUTC);
    float* hw1        = (float*)alloc((size_t)N * G_DIM);
    float* hw2        = (float*)alloc((size_t)N * G_DIM);
    float* x3         = (float*)alloc((size_t)N * G_DIM);
    float* pooled     = (float*)alloc((size_t)NGRAPH * G_DIM);
    float* msg_sorted = (float*)alloc((size_t)E * N_OUTC);   // chunk-major [5][E][4]
    (void)ws_size;

    // zero deg + cnt (first two regions, contiguous, each 16B-multiple)
    hipMemsetAsync(d_ws, 0, 2 * (((size_t)N * 4 + 15) & ~(size_t)15), stream);

    hist_kernel<<<ebl, 256, 0, stream>>>(ei, E, deg);
    scanA_kernel<<<nbl, 256, 0, stream>>>(deg, N, bsum);
    scanB_kernel<<<1, 256, 0, stream>>>(bsum, nbl, E, boff, rowptr, N);
    scanC_kernel<<<nbl, 256, 0, stream>>>(deg, N, boff, rowptr, dinv);
    slot_kernel<<<ebl, 256, 0, stream>>>(ei, E, rowptr, cnt, eid_at_slot, col_sorted);
    ecc_edge_kernel<<<ebl, 256, 0, stream>>>(e, x, eid_at_slot, col_sorted, E,
                                             w1, b1, w2, b2, w3, b3, msg_sorted);
    agg_kernel<<<(N + 63) / 64, 320, 0, stream>>>(msg_sorted, rowptr, N, E, agg);
    node1_kernel<<<nbl, 256, 0, stream>>>(agg, x, N, root, eb, g1w, hw1);
    gcn_gather_kernel<true><<<(N + 31) / 32, 256, 0, stream>>>(
        hw1, rowptr, col_sorted, dinv, N, g1b, g2w, hw2);
    gcn_gather_kernel<false><<<(N + 31) / 32, 256, 0, stream>>>(
        hw2, rowptr, col_sorted, dinv, N, g2b, nullptr, x3);
    pool_kernel<<<NGRAPH, 256, 0, stream>>>(x3, seg, N, pooled);
    head_kernel<<<(NGRAPH + 255) / 256, 256, 0, stream>>>(pooled, d1w, d1b, d2w, d2b, out);
}

// Round 5
// 324.939 us; speedup vs baseline: 11.7353x; 1.2189x over previous
//
#include <hip/hip_runtime.h>

// Model dims (fixed by the reference)
#define S_DIM   6
#define H_DIM   20
#define F_INN   8
#define N_OUTC  20
#define G_DIM   32
#define D1_DIM  16
#define NGRAPH  512

// ---------------------------------------------------------------------------
// 1) loc: per-edge local slot within its row (1 int atomic/edge, coalesced
//    loc write). cnt ends up holding deg[] — no separate histogram pass.
// ---------------------------------------------------------------------------
__global__ __launch_bounds__(256) void loc_kernel(
    const int* __restrict__ ei, int E, int* __restrict__ cnt,
    int* __restrict__ loc)
{
    int i = blockIdx.x * 256 + threadIdx.x;
    if (i >= E) return;
    loc[i] = atomicAdd(&cnt[ei[i]], 1);
}

// ---------------------------------------------------------------------------
// 2a) Per-block sums of deg (coalesced)
// ---------------------------------------------------------------------------
__global__ __launch_bounds__(256) void scanA_kernel(
    const int* __restrict__ deg, int N, int* __restrict__ bsum)
{
    int i = blockIdx.x * 256 + threadIdx.x;
    int v = (i < N) ? deg[i] : 0;
#pragma unroll
    for (int d = 1; d < 64; d <<= 1) v += __shfl_down(v, d, 64);
    __shared__ int ws[4];
    int wid = threadIdx.x >> 6;
    if ((threadIdx.x & 63) == 0) ws[wid] = v;
    __syncthreads();
    if (threadIdx.x == 0) bsum[blockIdx.x] = ws[0] + ws[1] + ws[2] + ws[3];
}

// ---------------------------------------------------------------------------
// 2b) Exclusive scan of block sums (<=256 blocks) in one small block
// ---------------------------------------------------------------------------
__global__ __launch_bounds__(256) void scanB_kernel(
    const int* __restrict__ bsum, int nb, int E,
    int* __restrict__ boff, int* __restrict__ rowptr, int N)
{
    int t = threadIdx.x;
    int v = (t < nb) ? bsum[t] : 0;
    int orig = v;
#pragma unroll
    for (int d = 1; d < 64; d <<= 1) {
        int u = __shfl_up(v, d, 64);
        if ((t & 63) >= d) v += u;
    }
    __shared__ int ws[4];
    int wid = t >> 6;
    if ((t & 63) == 63) ws[wid] = v;
    __syncthreads();
    int woff = 0;
    for (int w = 0; w < wid; ++w) woff += ws[w];
    if (t < nb) boff[t] = woff + v - orig;   // exclusive
    if (t == 0) rowptr[N] = E;
}

// ---------------------------------------------------------------------------
// 2c) Apply: block-local exclusive scan + block offset -> rowptr; dinv
// ---------------------------------------------------------------------------
__global__ __launch_bounds__(256) void scanC_kernel(
    const int* __restrict__ deg, int N, const int* __restrict__ boff,
    int* __restrict__ rowptr, float* __restrict__ dinv)
{
    int i = blockIdx.x * 256 + threadIdx.x;
    int t = threadIdx.x;
    int d0 = (i < N) ? deg[i] : 0;
    int v = d0;
#pragma unroll
    for (int d = 1; d < 64; d <<= 1) {
        int u = __shfl_up(v, d, 64);
        if ((t & 63) >= d) v += u;
    }
    __shared__ int ws[4];
    int wid = t >> 6;
    if ((t & 63) == 63) ws[wid] = v;
    __syncthreads();
    int woff = 0;
    for (int w = 0; w < wid; ++w) woff += ws[w];
    if (i < N) {
        rowptr[i] = boff[blockIdx.x] + woff + v - d0;  // exclusive prefix
        dinv[i] = rsqrtf((float)d0 + 1.0f);
    }
}

// ---------------------------------------------------------------------------
// 3) Build CSR slot arrays (NO atomics: p = rowptr[r] + loc[i])
// ---------------------------------------------------------------------------
__global__ __launch_bounds__(256) void build_kernel(
    const int* __restrict__ ei, int E, const int* __restrict__ rowptr,
    const int* __restrict__ loc,
    int* __restrict__ eid_at_slot, int* __restrict__ col_sorted)
{
    int i = blockIdx.x * 256 + threadIdx.x;
    if (i >= E) return;
    int p = rowptr[ei[i]] + loc[i];
    eid_at_slot[p] = i;
    col_sorted[p] = ei[E + i];
}

// ---------------------------------------------------------------------------
// 4) Fused ECC edge kernel + segmented row reduction (CSR order).
//    Messages staged in LDS; rows fully inside the block get plain coalesced
//    stores into agg; the <=2 boundary rows use unsafeAtomicAdd (agg pre-0).
// ---------------------------------------------------------------------------
__global__ __launch_bounds__(256) void ecc_fused_kernel(
    const float* __restrict__ e, const float* __restrict__ x,
    const int* __restrict__ eid_at_slot, const int* __restrict__ col_sorted,
    const int* __restrict__ rowptr, int N, int E,
    const float* __restrict__ w1, const float* __restrict__ b1,
    const float* __restrict__ w2, const float* __restrict__ b2,
    const float* __restrict__ w3, const float* __restrict__ b3,
    float* __restrict__ agg)
{
    __shared__ float4 lmsg[5][256];     // 20 KB
    __shared__ int rbounds[2];

    int t = threadIdx.x;
    int j0 = blockIdx.x * 256;
    int j = j0 + t;
    int jend = min(j0 + 256, E);

    if (t < 2) {
        int s = (t == 0) ? j0 : (jend - 1);
        // largest r in [0,N) with rowptr[r] <= s
        int lo = 0, hi = N - 1;
        while (lo < hi) {
            int m = (lo + hi + 1) >> 1;
            if (rowptr[m] <= s) lo = m; else hi = m - 1;
        }
        rbounds[t] = lo;
    }

    if (j < E) {
        int i = eid_at_slot[j];
        int c = col_sorted[j];

        float ef[S_DIM];
#pragma unroll
        for (int s = 0; s < S_DIM; ++s) ef[s] = e[(size_t)i * S_DIM + s];

        float h1[H_DIM];
#pragma unroll
        for (int jj = 0; jj < H_DIM; ++jj) {
            float a = b1[jj];
#pragma unroll
            for (int s = 0; s < S_DIM; ++s) a = fmaf(ef[s], w1[s * H_DIM + jj], a);
            h1[jj] = fmaxf(a, 0.0f);
        }

        float h2[H_DIM];
#pragma unroll
        for (int jj = 0; jj < H_DIM; ++jj) {
            float a = b2[jj];
#pragma unroll
            for (int k = 0; k < H_DIM; ++k) a = fmaf(h1[k], w2[k * H_DIM + jj], a);
            h2[jj] = fmaxf(a, 0.0f);
        }

        const float4* xp = (const float4*)&x[(size_t)c * F_INN];
        float4 xa = xp[0], xb = xp[1];
        float xf[F_INN] = {xa.x, xa.y, xa.z, xa.w, xb.x, xb.y, xb.z, xb.w};

        float msg[N_OUTC];
#pragma unroll
        for (int o = 0; o < N_OUTC; ++o) msg[o] = 0.0f;

        for (int f = 0; f < F_INN; ++f) {       // rolled: f stays wave-uniform
            float xv = xf[f];
#pragma unroll
            for (int o = 0; o < N_OUTC; ++o) {
                float w = b3[f * N_OUTC + o];
#pragma unroll
                for (int k = 0; k < H_DIM; ++k)
                    w = fmaf(h2[k], w3[k * (F_INN * N_OUTC) + f * N_OUTC + o], w);
                msg[o] = fmaf(xv, w, msg[o]);
            }
        }

        lmsg[0][t] = make_float4(msg[0],  msg[1],  msg[2],  msg[3]);
        lmsg[1][t] = make_float4(msg[4],  msg[5],  msg[6],  msg[7]);
        lmsg[2][t] = make_float4(msg[8],  msg[9],  msg[10], msg[11]);
        lmsg[3][t] = make_float4(msg[12], msg[13], msg[14], msg[15]);
        lmsg[4][t] = make_float4(msg[16], msg[17], msg[18], msg[19]);
    }
    __syncthreads();

    int r0 = rbounds[0], r1 = rbounds[1];
    int work = (r1 - r0 + 1) * 5;
    for (int w = t; w < work; w += 256) {
        int row = r0 + w / 5;
        int q = w - (w / 5) * 5;
        int a0 = rowptr[row], a1 = rowptr[row + 1];
        int s0 = max(a0, j0), s1 = min(a1, jend);
        float4 acc = make_float4(0.f, 0.f, 0.f, 0.f);
        for (int s = s0; s < s1; ++s) {
            float4 v = lmsg[q][s - j0];
            acc.x += v.x; acc.y += v.y; acc.z += v.z; acc.w += v.w;
        }
        float* dst = &agg[(size_t)row * N_OUTC + q * 4];
        if (a0 >= j0 && a1 <= jend) {
            *(float4*)dst = acc;              // row fully owned by this block
        } else {
            unsafeAtomicAdd(dst + 0, acc.x);  // boundary row (rare)
            unsafeAtomicAdd(dst + 1, acc.y);
            unsafeAtomicAdd(dst + 2, acc.z);
            unsafeAtomicAdd(dst + 3, acc.w);
        }
    }
}

// ---------------------------------------------------------------------------
// 5) Node transform: x1 = relu(agg + x@root + b); hw1 = x1 @ gcn1_w
// ---------------------------------------------------------------------------
__global__ __launch_bounds__(256) void node1_kernel(
    const float* __restrict__ agg, const float* __restrict__ x, int N,
    const float* __restrict__ root, const float* __restrict__ eb,
    const float* __restrict__ g1w,
    float* __restrict__ hw1)
{
    int n = blockIdx.x * 256 + threadIdx.x;
    if (n >= N) return;

    const float4* xp = (const float4*)&x[(size_t)n * F_INN];
    float4 xa = xp[0], xb = xp[1];
    float xf[F_INN] = {xa.x, xa.y, xa.z, xa.w, xb.x, xb.y, xb.z, xb.w};

    float x1[N_OUTC];
#pragma unroll
    for (int o = 0; o < N_OUTC; ++o) {
        float a = agg[(size_t)n * N_OUTC + o] + eb[o];
#pragma unroll
        for (int f = 0; f < F_INN; ++f) a = fmaf(xf[f], root[f * N_OUTC + o], a);
        x1[o] = fmaxf(a, 0.0f);
    }

    float4* hp = (float4*)&hw1[(size_t)n * G_DIM];
#pragma unroll
    for (int q = 0; q < G_DIM / 4; ++q) {
        float4 v;
        float* vv = &v.x;
#pragma unroll
        for (int u = 0; u < 4; ++u) {
            int g = q * 4 + u;
            float a = 0.0f;
#pragma unroll
            for (int o = 0; o < N_OUTC; ++o) a = fmaf(x1[o], g1w[o * G_DIM + g], a);
            vv[u] = a;
        }
        hp[q] = v;
    }
}

// ---------------------------------------------------------------------------
// 6) GCN gather, thread = (node, float4-chunk of 8). Block = 32 nodes x 8.
//    DO_MATMUL: stage x' in LDS, fused @W2 epilogue (w2 preloaded in LDS).
// ---------------------------------------------------------------------------
template<bool DO_MATMUL>
__global__ __launch_bounds__(256) void gcn_gather_kernel(
    const float* __restrict__ hw, const int* __restrict__ rowptr,
    const int* __restrict__ col_sorted, const float* __restrict__ dinv, int N,
    const float* __restrict__ bias, const float* __restrict__ w2,
    float* __restrict__ outbuf)
{
    __shared__ float x2s[32 * 33];
    __shared__ float w2s[G_DIM * G_DIM];

    int t = threadIdx.x;
    int nl = t >> 3;
    int q = t & 7;
    int n = blockIdx.x * 32 + nl;

    if (DO_MATMUL) {
        ((float4*)w2s)[t] = ((const float4*)w2)[t];
    }

    float4 xo = make_float4(0.f, 0.f, 0.f, 0.f);
    if (n < N) {
        int j0 = rowptr[n], j1 = rowptr[n + 1];
        float4 s = make_float4(0.f, 0.f, 0.f, 0.f);
        for (int j = j0; j < j1; ++j) {
            int c = col_sorted[j];
            float w = dinv[c];
            float4 v = *(const float4*)&hw[(size_t)c * G_DIM + q * 4];
            s.x = fmaf(w, v.x, s.x);
            s.y = fmaf(w, v.y, s.y);
            s.z = fmaf(w, v.z, s.z);
            s.w = fmaf(w, v.w, s.w);
        }
        float di = dinv[n];
        float sn = di * di;
        float4 self = *(const float4*)&hw[(size_t)n * G_DIM + q * 4];
        const float4 b4 = *(const float4*)&bias[q * 4];
        xo.x = fmaxf(fmaf(di, s.x, fmaf(sn, self.x, b4.x)), 0.0f);
        xo.y = fmaxf(fmaf(di, s.y, fmaf(sn, self.y, b4.y)), 0.0f);
        xo.z = fmaxf(fmaf(di, s.z, fmaf(sn, self.z, b4.z)), 0.0f);
        xo.w = fmaxf(fmaf(di, s.w, fmaf(sn, self.w, b4.w)), 0.0f);
    }

    if (DO_MATMUL) {
        x2s[nl * 33 + q * 4 + 0] = xo.x;
        x2s[nl * 33 + q * 4 + 1] = xo.y;
        x2s[nl * 33 + q * 4 + 2] = xo.z;
        x2s[nl * 33 + q * 4 + 3] = xo.w;
        __syncthreads();
        if (n < N) {
            float a0 = 0.f, a1 = 0.f, a2 = 0.f, a3 = 0.f;
            const float* xr = &x2s[nl * 33];
#pragma unroll
            for (int g = 0; g < G_DIM; ++g) {
                float xv = xr[g];
                a0 = fmaf(xv, w2s[g * G_DIM + q * 4 + 0], a0);
                a1 = fmaf(xv, w2s[g * G_DIM + q * 4 + 1], a1);
                a2 = fmaf(xv, w2s[g * G_DIM + q * 4 + 2], a2);
                a3 = fmaf(xv, w2s[g * G_DIM + q * 4 + 3], a3);
            }
            *(float4*)&outbuf[(size_t)n * G_DIM + q * 4] = make_float4(a0, a1, a2, a3);
        }
    } else {
        if (n < N)
            *(float4*)&outbuf[(size_t)n * G_DIM + q * 4] = xo;
    }
}

// ---------------------------------------------------------------------------
// 7) Pool: block per graph; inline binary search; 8x32 LDS reduce.
// ---------------------------------------------------------------------------
__global__ __launch_bounds__(256) void pool_kernel(
    const float* __restrict__ x3, const int* __restrict__ seg, int N,
    float* __restrict__ pooled)
{
    __shared__ float red[8][G_DIM];
    __shared__ int bounds[2];
    int g = blockIdx.x;
    int t = threadIdx.x;
    if (t < 2) {
        int target = g + t;
        int lo = 0, hi = N;
        while (lo < hi) {
            int m = (lo + hi) >> 1;
            if (seg[m] < target) lo = m + 1; else hi = m;
        }
        bounds[t] = lo;
    }
    __syncthreads();
    int n0 = bounds[0], n1 = bounds[1];
    int ch = t & (G_DIM - 1);
    int slice = t >> 5;
    float a = 0.0f;
    for (int n = n0 + slice; n < n1; n += 8)
        a += x3[(size_t)n * G_DIM + ch];
    red[slice][ch] = a;
    __syncthreads();
    if (slice == 0) {
        float s = red[0][ch];
#pragma unroll
        for (int k = 1; k < 8; ++k) s += red[k][ch];
        pooled[g * G_DIM + ch] = s;
    }
}

// ---------------------------------------------------------------------------
// 8) Head: out = (pooled @ d1_w + d1_b) @ d2_w + d2_b
// ---------------------------------------------------------------------------
__global__ __launch_bounds__(256) void head_kernel(
    const float* __restrict__ pooled,
    const float* __restrict__ d1w, const float* __restrict__ d1b,
    const float* __restrict__ d2w, const float* __restrict__ d2b,
    float* __restrict__ out)
{
    int i = blockIdx.x * 256 + threadIdx.x;
    if (i >= NGRAPH) return;

    float p[G_DIM];
#pragma unroll
    for (int g = 0; g < G_DIM; ++g) p[g] = pooled[i * G_DIM + g];

    float acc = d2b[0];
#pragma unroll
    for (int j = 0; j < D1_DIM; ++j) {
        float t = d1b[j];
#pragma unroll
        for (int g = 0; g < G_DIM; ++g) t = fmaf(p[g], d1w[g * D1_DIM + j], t);
        acc = fmaf(t, d2w[j], acc);
    }
    out[i] = acc;
}

// ---------------------------------------------------------------------------
extern "C" void kernel_launch(void* const* d_in, const int* in_sizes, int n_in,
                              void* d_out, int out_size, void* d_ws, size_t ws_size,
                              hipStream_t stream)
{
    const float* x    = (const float*)d_in[0];
    const float* e    = (const float*)d_in[1];
    const int*   ei   = (const int*)d_in[2];
    const int*   seg  = (const int*)d_in[3];
    const float* w1   = (const float*)d_in[4];
    const float* b1   = (const float*)d_in[5];
    const float* w2   = (const float*)d_in[6];
    const float* b2   = (const float*)d_in[7];
    const float* w3   = (const float*)d_in[8];
    const float* b3   = (const float*)d_in[9];
    const float* root = (const float*)d_in[10];
    const float* eb   = (const float*)d_in[11];
    const float* g1w  = (const float*)d_in[12];
    const float* g1b  = (const float*)d_in[13];
    const float* g2w  = (const float*)d_in[14];
    const float* g2b  = (const float*)d_in[15];
    const float* d1w  = (const float*)d_in[16];
    const float* d1b  = (const float*)d_in[17];
    const float* d2w  = (const float*)d_in[18];
    const float* d2b  = (const float*)d_in[19];

    const int N = in_sizes[3];            // 50000
    const int E = in_sizes[1] / S_DIM;    // 800000
    float* out = (float*)d_out;

    const int nbl = (N + 255) / 256;      // 196 blocks (<= 256 for scanB)
    const int ebl = (E + 255) / 256;

    // Workspace layout (each region 16B-aligned). cnt+agg first (zeroed).
    char* ws = (char*)d_ws;
    size_t off = 0;
    auto alloc = [&](size_t elems) -> char* {
        char* p = ws + off;
        off += ((elems * 4 + 15) & ~(size_t)15);
        return p;
    };
    int*   cnt        = (int*)  alloc(N);                    // zeroed (deg)
    float* agg        = (float*)alloc((size_t)N * N_OUTC);   // zeroed
    size_t zero_bytes = off;
    int*   rowptr     = (int*)  alloc(N + 1);
    int*   bsum       = (int*)  alloc(nbl);
    int*   boff       = (int*)  alloc(nbl);
    float* dinv       = (float*)alloc(N);
    int*   loc        = (int*)  alloc(E);
    int*   eid_at_slot= (int*)  alloc(E);
    int*   col_sorted = (int*)  alloc(E);
    float* hw1        = (float*)alloc((size_t)N * G_DIM);
    float* hw2        = (float*)alloc((size_t)N * G_DIM);
    float* x3         = (float*)alloc((size_t)N * G_DIM);
    float* pooled     = (float*)alloc((size_t)NGRAPH * G_DIM);
    (void)ws_size;

    hipMemsetAsync(d_ws, 0, zero_bytes, stream);

    loc_kernel<<<ebl, 256, 0, stream>>>(ei, E, cnt, loc);
    scanA_kernel<<<nbl, 256, 0, stream>>>(cnt, N, bsum);
    scanB_kernel<<<1, 256, 0, stream>>>(bsum, nbl, E, boff, rowptr, N);
    scanC_kernel<<<nbl, 256, 0, stream>>>(cnt, N, boff, rowptr, dinv);
    build_kernel<<<ebl, 256, 0, stream>>>(ei, E, rowptr, loc, eid_at_slot, col_sorted);
    ecc_fused_kernel<<<ebl, 256, 0, stream>>>(e, x, eid_at_slot, col_sorted,
                                              rowptr, N, E,
                                              w1, b1, w2, b2, w3, b3, agg);
    node1_kernel<<<nbl, 256, 0, stream>>>(agg, x, N, root, eb, g1w, hw1);
    gcn_gather_kernel<true><<<(N + 31) / 32, 256, 0, stream>>>(
        hw1, rowptr, col_sorted, dinv, N, g1b, g2w, hw2);
    gcn_gather_kernel<false><<<(N + 31) / 32, 256, 0, stream>>>(
        hw2, rowptr, col_sorted, dinv, N, g2b, nullptr, x3);
    pool_kernel<<<NGRAPH, 256, 0, stream>>>(x3, seg, N, pooled);
    head_kernel<<<(NGRAPH + 255) / 256, 256, 0, stream>>>(pooled, d1w, d1b, d2w, d2b, out);
}

// Round 6
// 314.646 us; speedup vs baseline: 12.1193x; 1.0327x over previous
//
#include <hip/hip_runtime.h>

// Model dims (fixed by the reference)
#define S_DIM   6
#define H_DIM   20
#define F_INN   8
#define N_OUTC  20
#define G_DIM   32
#define D1_DIM  16
#define NGRAPH  512

// ---------------------------------------------------------------------------
// 1) loc: per-edge local slot within its row (1 int atomic/edge, coalesced
//    loc write). cnt ends up holding deg[] — no separate histogram pass.
// ---------------------------------------------------------------------------
__global__ __launch_bounds__(256) void loc_kernel(
    const int* __restrict__ ei, int E, int* __restrict__ cnt,
    int* __restrict__ loc)
{
    int i = blockIdx.x * 256 + threadIdx.x;
    if (i >= E) return;
    loc[i] = atomicAdd(&cnt[ei[i]], 1);
}

// ---------------------------------------------------------------------------
// 2a) Per-block sums of deg (coalesced)
// ---------------------------------------------------------------------------
__global__ __launch_bounds__(256) void scanA_kernel(
    const int* __restrict__ deg, int N, int* __restrict__ bsum)
{
    int i = blockIdx.x * 256 + threadIdx.x;
    int v = (i < N) ? deg[i] : 0;
#pragma unroll
    for (int d = 1; d < 64; d <<= 1) v += __shfl_down(v, d, 64);
    __shared__ int ws[4];
    int wid = threadIdx.x >> 6;
    if ((threadIdx.x & 63) == 0) ws[wid] = v;
    __syncthreads();
    if (threadIdx.x == 0) bsum[blockIdx.x] = ws[0] + ws[1] + ws[2] + ws[3];
}

// ---------------------------------------------------------------------------
// 2b) Apply: each block first computes its own global offset from bsum
//    (<=256 entries, L2-resident), then block-local scan -> rowptr; dinv.
// ---------------------------------------------------------------------------
__global__ __launch_bounds__(256) void scanC_kernel(
    const int* __restrict__ deg, int N, const int* __restrict__ bsum, int nbl,
    int E, int* __restrict__ rowptr, float* __restrict__ dinv)
{
    __shared__ int ws[4];
    __shared__ int sboff;
    int t = threadIdx.x;

    // block offset = sum of bsum[0 .. blockIdx.x)
    {
        int v = (t < nbl && t < blockIdx.x) ? bsum[t] : 0;
#pragma unroll
        for (int d = 1; d < 64; d <<= 1) v += __shfl_down(v, d, 64);
        int wid = t >> 6;
        if ((t & 63) == 0) ws[wid] = v;
        __syncthreads();
        if (t == 0) sboff = ws[0] + ws[1] + ws[2] + ws[3];
        __syncthreads();
    }

    int i = blockIdx.x * 256 + t;
    int d0 = (i < N) ? deg[i] : 0;
    int v = d0;
#pragma unroll
    for (int d = 1; d < 64; d <<= 1) {
        int u = __shfl_up(v, d, 64);
        if ((t & 63) >= d) v += u;
    }
    __shared__ int ws2[4];
    int wid = t >> 6;
    if ((t & 63) == 63) ws2[wid] = v;
    __syncthreads();
    int woff = 0;
    for (int w = 0; w < wid; ++w) woff += ws2[w];
    if (i < N) {
        rowptr[i] = sboff + woff + v - d0;   // exclusive prefix
        dinv[i] = rsqrtf((float)d0 + 1.0f);
    }
    if (blockIdx.x == 0 && t == 0) rowptr[N] = E;
}

// ---------------------------------------------------------------------------
// 3) Build CSR slot arrays (NO atomics: p = rowptr[r] + loc[i])
// ---------------------------------------------------------------------------
__global__ __launch_bounds__(256) void build_kernel(
    const int* __restrict__ ei, int E, const int* __restrict__ rowptr,
    const int* __restrict__ loc,
    int* __restrict__ eid_at_slot, int* __restrict__ col_sorted)
{
    int i = blockIdx.x * 256 + threadIdx.x;
    if (i >= E) return;
    int p = rowptr[ei[i]] + loc[i];
    eid_at_slot[p] = i;
    col_sorted[p] = ei[E + i];
}

// ---------------------------------------------------------------------------
// 4) Fused ECC edge kernel + segmented row reduction (CSR order).
//    lmsg padded [5][257] to break the 5-way bank conflict in reduction.
// ---------------------------------------------------------------------------
__global__ __launch_bounds__(256) void ecc_fused_kernel(
    const float* __restrict__ e, const float* __restrict__ x,
    const int* __restrict__ eid_at_slot, const int* __restrict__ col_sorted,
    const int* __restrict__ rowptr, int N, int E,
    const float* __restrict__ w1, const float* __restrict__ b1,
    const float* __restrict__ w2, const float* __restrict__ b2,
    const float* __restrict__ w3, const float* __restrict__ b3,
    float* __restrict__ agg)
{
    __shared__ float4 lmsg[5][257];     // +1 pad: chunk stride 257*16B != 0 mod 128B
    __shared__ int rbounds[2];

    int t = threadIdx.x;
    int j0 = blockIdx.x * 256;
    int j = j0 + t;
    int jend = min(j0 + 256, E);

    if (t < 2) {
        int s = (t == 0) ? j0 : (jend - 1);
        // largest r in [0,N) with rowptr[r] <= s
        int lo = 0, hi = N - 1;
        while (lo < hi) {
            int m = (lo + hi + 1) >> 1;
            if (rowptr[m] <= s) lo = m; else hi = m - 1;
        }
        rbounds[t] = lo;
    }

    if (j < E) {
        int i = eid_at_slot[j];
        int c = col_sorted[j];

        float ef[S_DIM];
#pragma unroll
        for (int s = 0; s < S_DIM; ++s) ef[s] = e[(size_t)i * S_DIM + s];

        float h1[H_DIM];
#pragma unroll
        for (int jj = 0; jj < H_DIM; ++jj) {
            float a = b1[jj];
#pragma unroll
            for (int s = 0; s < S_DIM; ++s) a = fmaf(ef[s], w1[s * H_DIM + jj], a);
            h1[jj] = fmaxf(a, 0.0f);
        }

        float h2[H_DIM];
#pragma unroll
        for (int jj = 0; jj < H_DIM; ++jj) {
            float a = b2[jj];
#pragma unroll
            for (int k = 0; k < H_DIM; ++k) a = fmaf(h1[k], w2[k * H_DIM + jj], a);
            h2[jj] = fmaxf(a, 0.0f);
        }

        const float4* xp = (const float4*)&x[(size_t)c * F_INN];
        float4 xa = xp[0], xb = xp[1];
        float xf[F_INN] = {xa.x, xa.y, xa.z, xa.w, xb.x, xb.y, xb.z, xb.w};

        float msg[N_OUTC];
#pragma unroll
        for (int o = 0; o < N_OUTC; ++o) msg[o] = 0.0f;

        for (int f = 0; f < F_INN; ++f) {       // rolled: f stays wave-uniform
            float xv = xf[f];
#pragma unroll
            for (int o = 0; o < N_OUTC; ++o) {
                float w = b3[f * N_OUTC + o];
#pragma unroll
                for (int k = 0; k < H_DIM; ++k)
                    w = fmaf(h2[k], w3[k * (F_INN * N_OUTC) + f * N_OUTC + o], w);
                msg[o] = fmaf(xv, w, msg[o]);
            }
        }

        lmsg[0][t] = make_float4(msg[0],  msg[1],  msg[2],  msg[3]);
        lmsg[1][t] = make_float4(msg[4],  msg[5],  msg[6],  msg[7]);
        lmsg[2][t] = make_float4(msg[8],  msg[9],  msg[10], msg[11]);
        lmsg[3][t] = make_float4(msg[12], msg[13], msg[14], msg[15]);
        lmsg[4][t] = make_float4(msg[16], msg[17], msg[18], msg[19]);
    }
    __syncthreads();

    int r0 = rbounds[0], r1 = rbounds[1];
    int work = (r1 - r0 + 1) * 5;
    for (int w = t; w < work; w += 256) {
        int row = r0 + w / 5;
        int q = w - (w / 5) * 5;
        int a0 = rowptr[row], a1 = rowptr[row + 1];
        int s0 = max(a0, j0), s1 = min(a1, jend);
        float4 acc = make_float4(0.f, 0.f, 0.f, 0.f);
        for (int s = s0; s < s1; ++s) {
            float4 v = lmsg[q][s - j0];
            acc.x += v.x; acc.y += v.y; acc.z += v.z; acc.w += v.w;
        }
        float* dst = &agg[(size_t)row * N_OUTC + q * 4];
        if (a0 >= j0 && a1 <= jend) {
            *(float4*)dst = acc;              // row fully owned by this block
        } else {
            unsafeAtomicAdd(dst + 0, acc.x);  // boundary row (rare)
            unsafeAtomicAdd(dst + 1, acc.y);
            unsafeAtomicAdd(dst + 2, acc.z);
            unsafeAtomicAdd(dst + 3, acc.w);
        }
    }
}

// ---------------------------------------------------------------------------
// 5) Node transform: x1 = relu(agg + x@root + b);
//    hws1 = dinv[n] * (x1 @ gcn1_w)   (pre-scaled node features)
// ---------------------------------------------------------------------------
__global__ __launch_bounds__(256) void node1_kernel(
    const float* __restrict__ agg, const float* __restrict__ x,
    const float* __restrict__ dinv, int N,
    const float* __restrict__ root, const float* __restrict__ eb,
    const float* __restrict__ g1w,
    float* __restrict__ hws1)
{
    int n = blockIdx.x * 256 + threadIdx.x;
    if (n >= N) return;

    const float4* xp = (const float4*)&x[(size_t)n * F_INN];
    float4 xa = xp[0], xb = xp[1];
    float xf[F_INN] = {xa.x, xa.y, xa.z, xa.w, xb.x, xb.y, xb.z, xb.w};

    float x1[N_OUTC];
#pragma unroll
    for (int o = 0; o < N_OUTC; ++o) {
        float a = agg[(size_t)n * N_OUTC + o] + eb[o];
#pragma unroll
        for (int f = 0; f < F_INN; ++f) a = fmaf(xf[f], root[f * N_OUTC + o], a);
        x1[o] = fmaxf(a, 0.0f);
    }

    float di = dinv[n];
    float4* hp = (float4*)&hws1[(size_t)n * G_DIM];
#pragma unroll
    for (int q = 0; q < G_DIM / 4; ++q) {
        float4 v;
        float* vv = &v.x;
#pragma unroll
        for (int u = 0; u < 4; ++u) {
            int g = q * 4 + u;
            float a = 0.0f;
#pragma unroll
            for (int o = 0; o < N_OUTC; ++o) a = fmaf(x1[o], g1w[o * G_DIM + g], a);
            vv[u] = a * di;
        }
        hp[q] = v;
    }
}

// ---------------------------------------------------------------------------
// 6) GCN gather on pre-scaled features: x' = relu(di*(Σ hws[c] + hws[n]) + b).
//    Thread = (node, float4-chunk of 8); block = 32 nodes x 8.
//    DO_MATMUL: fused @W2 epilogue via LDS; output re-scaled by dinv (hws2).
// ---------------------------------------------------------------------------
template<bool DO_MATMUL>
__global__ __launch_bounds__(256) void gcn_gather_kernel(
    const float* __restrict__ hws, const int* __restrict__ rowptr,
    const int* __restrict__ col_sorted, const float* __restrict__ dinv, int N,
    const float* __restrict__ bias, const float* __restrict__ w2,
    float* __restrict__ outbuf)
{
    __shared__ float x2s[32 * 33];
    __shared__ float w2s[G_DIM * G_DIM];

    int t = threadIdx.x;
    int nl = t >> 3;
    int q = t & 7;
    int n = blockIdx.x * 32 + nl;

    if (DO_MATMUL) {
        ((float4*)w2s)[t] = ((const float4*)w2)[t];
    }

    float4 xo = make_float4(0.f, 0.f, 0.f, 0.f);
    float di = 0.0f;
    if (n < N) {
        di = dinv[n];
        int j0 = rowptr[n], j1 = rowptr[n + 1];
        float4 s = *(const float4*)&hws[(size_t)n * G_DIM + q * 4];  // self term
        for (int j = j0; j < j1; ++j) {
            int c = col_sorted[j];
            float4 v = *(const float4*)&hws[(size_t)c * G_DIM + q * 4];
            s.x += v.x; s.y += v.y; s.z += v.z; s.w += v.w;
        }
        const float4 b4 = *(const float4*)&bias[q * 4];
        xo.x = fmaxf(fmaf(di, s.x, b4.x), 0.0f);
        xo.y = fmaxf(fmaf(di, s.y, b4.y), 0.0f);
        xo.z = fmaxf(fmaf(di, s.z, b4.z), 0.0f);
        xo.w = fmaxf(fmaf(di, s.w, b4.w), 0.0f);
    }

    if (DO_MATMUL) {
        x2s[nl * 33 + q * 4 + 0] = xo.x;
        x2s[nl * 33 + q * 4 + 1] = xo.y;
        x2s[nl * 33 + q * 4 + 2] = xo.z;
        x2s[nl * 33 + q * 4 + 3] = xo.w;
        __syncthreads();
        if (n < N) {
            float a0 = 0.f, a1 = 0.f, a2 = 0.f, a3 = 0.f;
            const float* xr = &x2s[nl * 33];
#pragma unroll
            for (int g = 0; g < G_DIM; ++g) {
                float xv = xr[g];
                a0 = fmaf(xv, w2s[g * G_DIM + q * 4 + 0], a0);
                a1 = fmaf(xv, w2s[g * G_DIM + q * 4 + 1], a1);
                a2 = fmaf(xv, w2s[g * G_DIM + q * 4 + 2], a2);
                a3 = fmaf(xv, w2s[g * G_DIM + q * 4 + 3], a3);
            }
            // store pre-scaled for the next gather: hws2 = dinv * (x2 @ W2)
            *(float4*)&outbuf[(size_t)n * G_DIM + q * 4] =
                make_float4(a0 * di, a1 * di, a2 * di, a3 * di);
        }
    } else {
        if (n < N)
            *(float4*)&outbuf[(size_t)n * G_DIM + q * 4] = xo;   // x3 (unscaled)
    }
}

// ---------------------------------------------------------------------------
// 7) Pool + head fused: block per graph; binary search; 8x32 LDS reduce;
//    epilogue computes out[g] = (pooled@d1+b1)@d2+b2 in-block.
// ---------------------------------------------------------------------------
__global__ __launch_bounds__(256) void pool_head_kernel(
    const float* __restrict__ x3, const int* __restrict__ seg, int N,
    const float* __restrict__ d1w, const float* __restrict__ d1b,
    const float* __restrict__ d2w, const float* __restrict__ d2b,
    float* __restrict__ out)
{
    __shared__ float red[8][G_DIM];
    __shared__ float pvec[G_DIM];
    __shared__ int bounds[2];
    int g = blockIdx.x;
    int t = threadIdx.x;
    if (t < 2) {
        int target = g + t;
        int lo = 0, hi = N;
        while (lo < hi) {
            int m = (lo + hi) >> 1;
            if (seg[m] < target) lo = m + 1; else hi = m;
        }
        bounds[t] = lo;
    }
    __syncthreads();
    int n0 = bounds[0], n1 = bounds[1];
    int ch = t & (G_DIM - 1);
    int slice = t >> 5;
    float a = 0.0f;
    for (int n = n0 + slice; n < n1; n += 8)
        a += x3[(size_t)n * G_DIM + ch];
    red[slice][ch] = a;
    __syncthreads();
    if (slice == 0) {
        float s = red[0][ch];
#pragma unroll
        for (int k = 1; k < 8; ++k) s += red[k][ch];
        pvec[ch] = s;
    }
    __syncthreads();
    if (t < D1_DIM) {
        float tj = d1b[t];
#pragma unroll
        for (int gg = 0; gg < G_DIM; ++gg)
            tj = fmaf(pvec[gg], d1w[gg * D1_DIM + t], tj);
        float acc = tj * d2w[t];
#pragma unroll
        for (int d = 1; d < D1_DIM; d <<= 1) acc += __shfl_down(acc, d, 64);
        if (t == 0) out[g] = acc + d2b[0];
    }
}

// ---------------------------------------------------------------------------
extern "C" void kernel_launch(void* const* d_in, const int* in_sizes, int n_in,
                              void* d_out, int out_size, void* d_ws, size_t ws_size,
                              hipStream_t stream)
{
    const float* x    = (const float*)d_in[0];
    const float* e    = (const float*)d_in[1];
    const int*   ei   = (const int*)d_in[2];
    const int*   seg  = (const int*)d_in[3];
    const float* w1   = (const float*)d_in[4];
    const float* b1   = (const float*)d_in[5];
    const float* w2   = (const float*)d_in[6];
    const float* b2   = (const float*)d_in[7];
    const float* w3   = (const float*)d_in[8];
    const float* b3   = (const float*)d_in[9];
    const float* root = (const float*)d_in[10];
    const float* eb   = (const float*)d_in[11];
    const float* g1w  = (const float*)d_in[12];
    const float* g1b  = (const float*)d_in[13];
    const float* g2w  = (const float*)d_in[14];
    const float* g2b  = (const float*)d_in[15];
    const float* d1w  = (const float*)d_in[16];
    const float* d1b  = (const float*)d_in[17];
    const float* d2w  = (const float*)d_in[18];
    const float* d2b  = (const float*)d_in[19];

    const int N = in_sizes[3];            // 50000
    const int E = in_sizes[1] / S_DIM;    // 800000
    float* out = (float*)d_out;

    const int nbl = (N + 255) / 256;      // 196 blocks (<= 256 for scanC)
    const int ebl = (E + 255) / 256;

    // Workspace layout (each region 16B-aligned). cnt+agg first (zeroed).
    char* ws = (char*)d_ws;
    size_t off = 0;
    auto alloc = [&](size_t elems) -> char* {
        char* p = ws + off;
        off += ((elems * 4 + 15) & ~(size_t)15);
        return p;
    };
    int*   cnt        = (int*)  alloc(N);                    // zeroed (deg)
    float* agg        = (float*)alloc((size_t)N * N_OUTC);   // zeroed
    size_t zero_bytes = off;
    int*   rowptr     = (int*)  alloc(N + 1);
    int*   bsum       = (int*)  alloc(nbl);
    float* dinv       = (float*)alloc(N);
    int*   loc        = (int*)  alloc(E);
    int*   eid_at_slot= (int*)  alloc(E);
    int*   col_sorted = (int*)  alloc(E);
    float* hws1       = (float*)alloc((size_t)N * G_DIM);
    float* hws2       = (float*)alloc((size_t)N * G_DIM);
    float* x3         = (float*)alloc((size_t)N * G_DIM);
    (void)ws_size;

    hipMemsetAsync(d_ws, 0, zero_bytes, stream);

    loc_kernel<<<ebl, 256, 0, stream>>>(ei, E, cnt, loc);
    scanA_kernel<<<nbl, 256, 0, stream>>>(cnt, N, bsum);
    scanC_kernel<<<nbl, 256, 0, stream>>>(cnt, N, bsum, nbl, E, rowptr, dinv);
    build_kernel<<<ebl, 256, 0, stream>>>(ei, E, rowptr, loc, eid_at_slot, col_sorted);
    ecc_fused_kernel<<<ebl, 256, 0, stream>>>(e, x, eid_at_slot, col_sorted,
                                              rowptr, N, E,
                                              w1, b1, w2, b2, w3, b3, agg);
    node1_kernel<<<nbl, 256, 0, stream>>>(agg, x, dinv, N, root, eb, g1w, hws1);
    gcn_gather_kernel<true><<<(N + 31) / 32, 256, 0, stream>>>(
        hws1, rowptr, col_sorted, dinv, N, g1b, g2w, hws2);
    gcn_gather_kernel<false><<<(N + 31) / 32, 256, 0, stream>>>(
        hws2, rowptr, col_sorted, dinv, N, g2b, nullptr, x3);
    pool_head_kernel<<<NGRAPH, 256, 0, stream>>>(x3, seg, N, d1w, d1b, d2w, d2b, out);
}

// Round 7
// 306.801 us; speedup vs baseline: 12.4291x; 1.0256x over previous
//
#include <hip/hip_runtime.h>

// Model dims (fixed by the reference)
#define S_DIM   6
#define H_DIM   20
#define F_INN   8
#define N_OUTC  20
#define G_DIM   32
#define D1_DIM  16
#define NGRAPH  512

typedef short short8 __attribute__((ext_vector_type(8)));
typedef float floatx4 __attribute__((ext_vector_type(4)));

__device__ __forceinline__ unsigned short f2bf(float f) {
    unsigned u = __float_as_uint(f);
    return (unsigned short)((u + 0x8000u) >> 16);   // RTN (ties up)
}
__device__ __forceinline__ float bf2f(unsigned short s) {
    return __uint_as_float(((unsigned)s) << 16);
}

// ---------------------------------------------------------------------------
// 1) loc: per-edge local slot within its row (1 int atomic/edge). cnt -> deg.
// ---------------------------------------------------------------------------
__global__ __launch_bounds__(256) void loc_kernel(
    const int* __restrict__ ei, int E, int* __restrict__ cnt,
    int* __restrict__ loc)
{
    int i = blockIdx.x * 256 + threadIdx.x;
    if (i >= E) return;
    loc[i] = atomicAdd(&cnt[ei[i]], 1);
}

// ---------------------------------------------------------------------------
// 2a) Per-block sums of deg (coalesced)
// ---------------------------------------------------------------------------
__global__ __launch_bounds__(256) void scanA_kernel(
    const int* __restrict__ deg, int N, int* __restrict__ bsum)
{
    int i = blockIdx.x * 256 + threadIdx.x;
    int v = (i < N) ? deg[i] : 0;
#pragma unroll
    for (int d = 1; d < 64; d <<= 1) v += __shfl_down(v, d, 64);
    __shared__ int ws[4];
    int wid = threadIdx.x >> 6;
    if ((threadIdx.x & 63) == 0) ws[wid] = v;
    __syncthreads();
    if (threadIdx.x == 0) bsum[blockIdx.x] = ws[0] + ws[1] + ws[2] + ws[3];
}

// ---------------------------------------------------------------------------
// 2b) Apply: block offset from bsum, block-local scan -> rowptr; dinv
// ---------------------------------------------------------------------------
__global__ __launch_bounds__(256) void scanC_kernel(
    const int* __restrict__ deg, int N, const int* __restrict__ bsum, int nbl,
    int E, int* __restrict__ rowptr, float* __restrict__ dinv)
{
    __shared__ int ws[4];
    __shared__ int sboff;
    int t = threadIdx.x;
    {
        int v = (t < nbl && t < blockIdx.x) ? bsum[t] : 0;
#pragma unroll
        for (int d = 1; d < 64; d <<= 1) v += __shfl_down(v, d, 64);
        int wid = t >> 6;
        if ((t & 63) == 0) ws[wid] = v;
        __syncthreads();
        if (t == 0) sboff = ws[0] + ws[1] + ws[2] + ws[3];
        __syncthreads();
    }

    int i = blockIdx.x * 256 + t;
    int d0 = (i < N) ? deg[i] : 0;
    int v = d0;
#pragma unroll
    for (int d = 1; d < 64; d <<= 1) {
        int u = __shfl_up(v, d, 64);
        if ((t & 63) >= d) v += u;
    }
    __shared__ int ws2[4];
    int wid = t >> 6;
    if ((t & 63) == 63) ws2[wid] = v;
    __syncthreads();
    int woff = 0;
    for (int w = 0; w < wid; ++w) woff += ws2[w];
    if (i < N) {
        rowptr[i] = sboff + woff + v - d0;
        dinv[i] = rsqrtf((float)d0 + 1.0f);
    }
    if (blockIdx.x == 0 && t == 0) rowptr[N] = E;
}

// ---------------------------------------------------------------------------
// 3) Build CSR slot arrays (no atomics: p = rowptr[r] + loc[i])
// ---------------------------------------------------------------------------
__global__ __launch_bounds__(256) void build_kernel(
    const int* __restrict__ ei, int E, const int* __restrict__ rowptr,
    const int* __restrict__ loc,
    int* __restrict__ eid_at_slot, int* __restrict__ col_sorted)
{
    int i = blockIdx.x * 256 + threadIdx.x;
    if (i >= E) return;
    int p = rowptr[ei[i]] + loc[i];
    eid_at_slot[p] = i;
    col_sorted[p] = ei[E + i];
}

// ---------------------------------------------------------------------------
// 4) ECC with MFMA einsum + segmented row reduction (CSR order).
//    Per-edge MLP (fp32 VALU) -> h2,x to LDS (bf16) ->
//    msg = [p | x] @ [W3' ; b3] via mfma_f32_16x16x32_bf16, K=192 ->
//    lmsg LDS -> segmented reduce -> agg (boundary rows via unsafeAtomicAdd).
//    B (bf16, fragment-ready) is staged in LDS aliased with lmsg.
// ---------------------------------------------------------------------------
__global__ __launch_bounds__(256) void ecc_mfma_kernel(
    const float* __restrict__ e, const float* __restrict__ x,
    const int* __restrict__ eid_at_slot, const int* __restrict__ col_sorted,
    const int* __restrict__ rowptr, int N, int E,
    const float* __restrict__ w1, const float* __restrict__ b1,
    const float* __restrict__ w2, const float* __restrict__ b2,
    const float* __restrict__ w3, const float* __restrict__ b3,
    float* __restrict__ agg)
{
    // union region: B bf16[6144] (12.3 KB) lives until frags loaded, then
    // lmsg float[256][20] (20.5 KB) reuses it.
    __shared__ char ubuf[256 * N_OUTC * 4];
    __shared__ unsigned short h2b[256][N_OUTC];   // 10.2 KB
    __shared__ unsigned short xb[256][F_INN];     // 4 KB
    __shared__ int rbounds[2];

    unsigned short* Bl = (unsigned short*)ubuf;
    float* lmsg = (float*)ubuf;

    int t = threadIdx.x;
    int j0 = blockIdx.x * 256;
    int jend = min(j0 + 256, E);
    int j = j0 + t;

    if (t < 2) {
        int s = (t == 0) ? j0 : (jend - 1);
        int lo = 0, hi = N - 1;
        while (lo < hi) {
            int m = (lo + hi + 1) >> 1;
            if (rowptr[m] <= s) lo = m; else hi = m - 1;
        }
        rbounds[t] = lo;
    }

    // ---- stage B into LDS, fragment-ready: [s][nt][quad][n][j] (bf16) ----
    // B[K][o]: K = 32s + quad*8 + j ; o = n + 16*nt
    //   K<160: w3[(K>>3)*160 + (K&7)*20 + o] ; 160<=K<168: b3[(K-160)*20+o]
    for (int idx = t; idx < 6144; idx += 256) {
        int jj   = idx & 7;
        int n    = (idx >> 3) & 15;
        int quad = (idx >> 7) & 3;
        int nt   = (idx >> 9) & 1;
        int s    = idx >> 10;
        int K = 32 * s + quad * 8 + jj;
        int o = n + 16 * nt;
        float v = 0.0f;
        if (o < N_OUTC) {
            if (K < 160)      v = w3[(K >> 3) * 160 + (K & 7) * N_OUTC + o];
            else if (K < 168) v = b3[(K - 160) * N_OUTC + o];
        }
        Bl[idx] = f2bf(v);
    }

    // ---- per-edge MLP (fp32) ----
    if (j < E) {
        int i = eid_at_slot[j];
        int c = col_sorted[j];

        float ef[S_DIM];
#pragma unroll
        for (int s = 0; s < S_DIM; ++s) ef[s] = e[(size_t)i * S_DIM + s];

        float h1[H_DIM];
#pragma unroll
        for (int jj = 0; jj < H_DIM; ++jj) {
            float a = b1[jj];
#pragma unroll
            for (int s = 0; s < S_DIM; ++s) a = fmaf(ef[s], w1[s * H_DIM + jj], a);
            h1[jj] = fmaxf(a, 0.0f);
        }

        float h2[H_DIM];
#pragma unroll
        for (int jj = 0; jj < H_DIM; ++jj) {
            float a = b2[jj];
#pragma unroll
            for (int k = 0; k < H_DIM; ++k) a = fmaf(h1[k], w2[k * H_DIM + jj], a);
            h2[jj] = fmaxf(a, 0.0f);
        }

        const float4* xp = (const float4*)&x[(size_t)c * F_INN];
        float4 xa = xp[0], xb4 = xp[1];
        float xf[F_INN] = {xa.x, xa.y, xa.z, xa.w, xb4.x, xb4.y, xb4.z, xb4.w};

#pragma unroll
        for (int o = 0; o < N_OUTC; ++o) h2b[t][o] = f2bf(h2[o]);
#pragma unroll
        for (int f = 0; f < F_INN; ++f) xb[t][f] = f2bf(xf[f]);
    } else {
#pragma unroll
        for (int o = 0; o < N_OUTC; ++o) h2b[t][o] = 0;
#pragma unroll
        for (int f = 0; f < F_INN; ++f) xb[t][f] = 0;
    }
    __syncthreads();

    // ---- load B fragments to registers ----
    int lane = t & 63;
    int quad = lane >> 4;
    int n = lane & 15;
    short8 Bf[12];
#pragma unroll
    for (int s = 0; s < 6; ++s)
#pragma unroll
        for (int nt = 0; nt < 2; ++nt)
            Bf[s * 2 + nt] = *(const short8*)&Bl[((((s * 2 + nt) * 4 + quad) * 16 + n) * 8)];
    __syncthreads();   // B region now dead -> lmsg may overwrite

    // ---- MFMA: 4 m-tiles per wave ----
    int w = t >> 6;
#pragma unroll
    for (int T = 0; T < 4; ++T) {
        int base = w * 64 + T * 16;
        int m = base + n;                       // edge-local index for A-rows

        const short8 xv8 = *(const short8*)&xb[m][0];
        float xfl[F_INN];
#pragma unroll
        for (int jj = 0; jj < F_INN; ++jj) xfl[jj] = bf2f((unsigned short)xv8[jj]);

        floatx4 acc0 = {0.f, 0.f, 0.f, 0.f};
        floatx4 acc1 = {0.f, 0.f, 0.f, 0.f};
#pragma unroll
        for (int s = 0; s < 6; ++s) {
            short8 A = {0, 0, 0, 0, 0, 0, 0, 0};
            if (s < 5) {
                float h = bf2f(h2b[m][4 * s + quad]);
#pragma unroll
                for (int jj = 0; jj < F_INN; ++jj)
                    A[jj] = (short)f2bf(h * xfl[jj]);
            } else if (quad == 0) {
                A = xv8;                        // b3 rows: p = x
            }
            acc0 = __builtin_amdgcn_mfma_f32_16x16x32_bf16(A, Bf[s * 2 + 0], acc0, 0, 0, 0);
            acc1 = __builtin_amdgcn_mfma_f32_16x16x32_bf16(A, Bf[s * 2 + 1], acc1, 0, 0, 0);
        }

        // C: col = n (+16 for acc1), row = base + quad*4 + r
#pragma unroll
        for (int r = 0; r < 4; ++r) {
            int row = base + quad * 4 + r;
            lmsg[row * N_OUTC + n] = acc0[r];
            if (n < 4) lmsg[row * N_OUTC + 16 + n] = acc1[r];
        }
    }
    __syncthreads();

    // ---- segmented row reduction into agg ----
    int r0 = rbounds[0], r1 = rbounds[1];
    int work = (r1 - r0 + 1) * 5;
    for (int ww = t; ww < work; ww += 256) {
        int row = r0 + ww / 5;
        int q = ww - (ww / 5) * 5;
        int a0 = rowptr[row], a1 = rowptr[row + 1];
        int s0 = max(a0, j0), s1 = min(a1, jend);
        float4 acc = make_float4(0.f, 0.f, 0.f, 0.f);
        for (int s = s0; s < s1; ++s) {
            const float4 v = *(const float4*)&lmsg[(s - j0) * N_OUTC + q * 4];
            acc.x += v.x; acc.y += v.y; acc.z += v.z; acc.w += v.w;
        }
        float* dst = &agg[(size_t)row * N_OUTC + q * 4];
        if (a0 >= j0 && a1 <= jend) {
            *(float4*)dst = acc;
        } else {
            unsafeAtomicAdd(dst + 0, acc.x);
            unsafeAtomicAdd(dst + 1, acc.y);
            unsafeAtomicAdd(dst + 2, acc.z);
            unsafeAtomicAdd(dst + 3, acc.w);
        }
    }
}

// ---------------------------------------------------------------------------
// 5) Node transform: x1 = relu(agg + x@root + b); hws1 = dinv*(x1@gcn1_w)
// ---------------------------------------------------------------------------
__global__ __launch_bounds__(256) void node1_kernel(
    const float* __restrict__ agg, const float* __restrict__ x,
    const float* __restrict__ dinv, int N,
    const float* __restrict__ root, const float* __restrict__ eb,
    const float* __restrict__ g1w,
    float* __restrict__ hws1)
{
    int n = blockIdx.x * 256 + threadIdx.x;
    if (n >= N) return;

    const float4* xp = (const float4*)&x[(size_t)n * F_INN];
    float4 xa = xp[0], xb = xp[1];
    float xf[F_INN] = {xa.x, xa.y, xa.z, xa.w, xb.x, xb.y, xb.z, xb.w};

    float x1[N_OUTC];
#pragma unroll
    for (int o = 0; o < N_OUTC; ++o) {
        float a = agg[(size_t)n * N_OUTC + o] + eb[o];
#pragma unroll
        for (int f = 0; f < F_INN; ++f) a = fmaf(xf[f], root[f * N_OUTC + o], a);
        x1[o] = fmaxf(a, 0.0f);
    }

    float di = dinv[n];
    float4* hp = (float4*)&hws1[(size_t)n * G_DIM];
#pragma unroll
    for (int q = 0; q < G_DIM / 4; ++q) {
        float4 v;
        float* vv = &v.x;
#pragma unroll
        for (int u = 0; u < 4; ++u) {
            int g = q * 4 + u;
            float a = 0.0f;
#pragma unroll
            for (int o = 0; o < N_OUTC; ++o) a = fmaf(x1[o], g1w[o * G_DIM + g], a);
            vv[u] = a * di;
        }
        hp[q] = v;
    }
}

// ---------------------------------------------------------------------------
// 6) GCN gather on pre-scaled features. Thread = (node, chunk of 8).
// ---------------------------------------------------------------------------
template<bool DO_MATMUL>
__global__ __launch_bounds__(256) void gcn_gather_kernel(
    const float* __restrict__ hws, const int* __restrict__ rowptr,
    const int* __restrict__ col_sorted, const float* __restrict__ dinv, int N,
    const float* __restrict__ bias, const float* __restrict__ w2,
    float* __restrict__ outbuf)
{
    __shared__ float x2s[32 * 33];
    __shared__ float w2s[G_DIM * G_DIM];

    int t = threadIdx.x;
    int nl = t >> 3;
    int q = t & 7;
    int n = blockIdx.x * 32 + nl;

    if (DO_MATMUL) {
        ((float4*)w2s)[t] = ((const float4*)w2)[t];
    }

    float4 xo = make_float4(0.f, 0.f, 0.f, 0.f);
    float di = 0.0f;
    if (n < N) {
        di = dinv[n];
        int j0 = rowptr[n], j1 = rowptr[n + 1];
        float4 s = *(const float4*)&hws[(size_t)n * G_DIM + q * 4];
        for (int j = j0; j < j1; ++j) {
            int c = col_sorted[j];
            float4 v = *(const float4*)&hws[(size_t)c * G_DIM + q * 4];
            s.x += v.x; s.y += v.y; s.z += v.z; s.w += v.w;
        }
        const float4 b4 = *(const float4*)&bias[q * 4];
        xo.x = fmaxf(fmaf(di, s.x, b4.x), 0.0f);
        xo.y = fmaxf(fmaf(di, s.y, b4.y), 0.0f);
        xo.z = fmaxf(fmaf(di, s.z, b4.z), 0.0f);
        xo.w = fmaxf(fmaf(di, s.w, b4.w), 0.0f);
    }

    if (DO_MATMUL) {
        x2s[nl * 33 + q * 4 + 0] = xo.x;
        x2s[nl * 33 + q * 4 + 1] = xo.y;
        x2s[nl * 33 + q * 4 + 2] = xo.z;
        x2s[nl * 33 + q * 4 + 3] = xo.w;
        __syncthreads();
        if (n < N) {
            float a0 = 0.f, a1 = 0.f, a2 = 0.f, a3 = 0.f;
            const float* xr = &x2s[nl * 33];
#pragma unroll
            for (int g = 0; g < G_DIM; ++g) {
                float xv = xr[g];
                a0 = fmaf(xv, w2s[g * G_DIM + q * 4 + 0], a0);
                a1 = fmaf(xv, w2s[g * G_DIM + q * 4 + 1], a1);
                a2 = fmaf(xv, w2s[g * G_DIM + q * 4 + 2], a2);
                a3 = fmaf(xv, w2s[g * G_DIM + q * 4 + 3], a3);
            }
            *(float4*)&outbuf[(size_t)n * G_DIM + q * 4] =
                make_float4(a0 * di, a1 * di, a2 * di, a3 * di);
        }
    } else {
        if (n < N)
            *(float4*)&outbuf[(size_t)n * G_DIM + q * 4] = xo;
    }
}

// ---------------------------------------------------------------------------
// 7) Pool + head fused
// ---------------------------------------------------------------------------
__global__ __launch_bounds__(256) void pool_head_kernel(
    const float* __restrict__ x3, const int* __restrict__ seg, int N,
    const float* __restrict__ d1w, const float* __restrict__ d1b,
    const float* __restrict__ d2w, const float* __restrict__ d2b,
    float* __restrict__ out)
{
    __shared__ float red[8][G_DIM];
    __shared__ float pvec[G_DIM];
    __shared__ int bounds[2];
    int g = blockIdx.x;
    int t = threadIdx.x;
    if (t < 2) {
        int target = g + t;
        int lo = 0, hi = N;
        while (lo < hi) {
            int m = (lo + hi) >> 1;
            if (seg[m] < target) lo = m + 1; else hi = m;
        }
        bounds[t] = lo;
    }
    __syncthreads();
    int n0 = bounds[0], n1 = bounds[1];
    int ch = t & (G_DIM - 1);
    int slice = t >> 5;
    float a = 0.0f;
    for (int n = n0 + slice; n < n1; n += 8)
        a += x3[(size_t)n * G_DIM + ch];
    red[slice][ch] = a;
    __syncthreads();
    if (slice == 0) {
        float s = red[0][ch];
#pragma unroll
        for (int k = 1; k < 8; ++k) s += red[k][ch];
        pvec[ch] = s;
    }
    __syncthreads();
    // head: all 64 lanes of wave 0 participate (defined acc everywhere)
    if (t < 64) {
        float acc = 0.0f;
        if (t < D1_DIM) {
            float tj = d1b[t];
#pragma unroll
            for (int gg = 0; gg < G_DIM; ++gg)
                tj = fmaf(pvec[gg], d1w[gg * D1_DIM + t], tj);
            acc = tj * d2w[t];
        }
#pragma unroll
        for (int d = 1; d < D1_DIM; d <<= 1) acc += __shfl_down(acc, d, 64);
        if (t == 0) out[g] = acc + d2b[0];
    }
}

// ---------------------------------------------------------------------------
extern "C" void kernel_launch(void* const* d_in, const int* in_sizes, int n_in,
                              void* d_out, int out_size, void* d_ws, size_t ws_size,
                              hipStream_t stream)
{
    const float* x    = (const float*)d_in[0];
    const float* e    = (const float*)d_in[1];
    const int*   ei   = (const int*)d_in[2];
    const int*   seg  = (const int*)d_in[3];
    const float* w1   = (const float*)d_in[4];
    const float* b1   = (const float*)d_in[5];
    const float* w2   = (const float*)d_in[6];
    const float* b2   = (const float*)d_in[7];
    const float* w3   = (const float*)d_in[8];
    const float* b3   = (const float*)d_in[9];
    const float* root = (const float*)d_in[10];
    const float* eb   = (const float*)d_in[11];
    const float* g1w  = (const float*)d_in[12];
    const float* g1b  = (const float*)d_in[13];
    const float* g2w  = (const float*)d_in[14];
    const float* g2b  = (const float*)d_in[15];
    const float* d1w  = (const float*)d_in[16];
    const float* d1b  = (const float*)d_in[17];
    const float* d2w  = (const float*)d_in[18];
    const float* d2b  = (const float*)d_in[19];

    const int N = in_sizes[3];            // 50000
    const int E = in_sizes[1] / S_DIM;    // 800000
    float* out = (float*)d_out;

    const int nbl = (N + 255) / 256;      // 196 (<= 256 for scanC)
    const int ebl = (E + 255) / 256;

    char* ws = (char*)d_ws;
    size_t off = 0;
    auto alloc = [&](size_t elems) -> char* {
        char* p = ws + off;
        off += ((elems * 4 + 15) & ~(size_t)15);
        return p;
    };
    int*   cnt        = (int*)  alloc(N);                    // zeroed (deg)
    float* agg        = (float*)alloc((size_t)N * N_OUTC);   // zeroed
    size_t zero_bytes = off;
    int*   rowptr     = (int*)  alloc(N + 1);
    int*   bsum       = (int*)  alloc(nbl);
    float* dinv       = (float*)alloc(N);
    int*   loc        = (int*)  alloc(E);
    int*   eid_at_slot= (int*)  alloc(E);
    int*   col_sorted = (int*)  alloc(E);
    float* hws1       = (float*)alloc((size_t)N * G_DIM);
    float* hws2       = (float*)alloc((size_t)N * G_DIM);
    float* x3         = (float*)alloc((size_t)N * G_DIM);
    (void)ws_size;

    hipMemsetAsync(d_ws, 0, zero_bytes, stream);

    loc_kernel<<<ebl, 256, 0, stream>>>(ei, E, cnt, loc);
    scanA_kernel<<<nbl, 256, 0, stream>>>(cnt, N, bsum);
    scanC_kernel<<<nbl, 256, 0, stream>>>(cnt, N, bsum, nbl, E, rowptr, dinv);
    build_kernel<<<ebl, 256, 0, stream>>>(ei, E, rowptr, loc, eid_at_slot, col_sorted);
    ecc_mfma_kernel<<<ebl, 256, 0, stream>>>(e, x, eid_at_slot, col_sorted,
                                             rowptr, N, E,
                                             w1, b1, w2, b2, w3, b3, agg);
    node1_kernel<<<nbl, 256, 0, stream>>>(agg, x, dinv, N, root, eb, g1w, hws1);
    gcn_gather_kernel<true><<<(N + 31) / 32, 256, 0, stream>>>(
        hws1, rowptr, col_sorted, dinv, N, g1b, g2w, hws2);
    gcn_gather_kernel<false><<<(N + 31) / 32, 256, 0, stream>>>(
        hws2, rowptr, col_sorted, dinv, N, g2b, nullptr, x3);
    pool_head_kernel<<<NGRAPH, 256, 0, stream>>>(x3, seg, N, d1w, d1b, d2w, d2b, out);
}

// Round 8
// 292.213 us; speedup vs baseline: 13.0496x; 1.0499x over previous
//
#include <hip/hip_runtime.h>

// Model dims (fixed by the reference)
#define S_DIM   6
#define H_DIM   20
#define F_INN   8
#define N_OUTC  20
#define G_DIM   32
#define D1_DIM  16
#define NGRAPH  512

typedef short short8 __attribute__((ext_vector_type(8)));
typedef float floatx4 __attribute__((ext_vector_type(4)));

__device__ __forceinline__ unsigned short f2bf(float f) {
    unsigned u = __float_as_uint(f);
    return (unsigned short)((u + 0x8000u) >> 16);   // RTN (ties up)
}
__device__ __forceinline__ float bf2f(unsigned short s) {
    return __uint_as_float(((unsigned)s) << 16);
}

// ---------------------------------------------------------------------------
// 1) loc: per-edge local slot within its row (1 int atomic/edge). cnt -> deg.
// ---------------------------------------------------------------------------
__global__ __launch_bounds__(256) void loc_kernel(
    const int* __restrict__ ei, int E, int* __restrict__ cnt,
    int* __restrict__ loc)
{
    int i = blockIdx.x * 256 + threadIdx.x;
    if (i >= E) return;
    loc[i] = atomicAdd(&cnt[ei[i]], 1);
}

// ---------------------------------------------------------------------------
// 2a) Per-block sums of deg (coalesced)
// ---------------------------------------------------------------------------
__global__ __launch_bounds__(256) void scanA_kernel(
    const int* __restrict__ deg, int N, int* __restrict__ bsum)
{
    int i = blockIdx.x * 256 + threadIdx.x;
    int v = (i < N) ? deg[i] : 0;
#pragma unroll
    for (int d = 1; d < 64; d <<= 1) v += __shfl_down(v, d, 64);
    __shared__ int ws[4];
    int wid = threadIdx.x >> 6;
    if ((threadIdx.x & 63) == 0) ws[wid] = v;
    __syncthreads();
    if (threadIdx.x == 0) bsum[blockIdx.x] = ws[0] + ws[1] + ws[2] + ws[3];
}

// ---------------------------------------------------------------------------
// 2b) Apply: block offset from bsum, block-local scan -> rowptr; dinv
// ---------------------------------------------------------------------------
__global__ __launch_bounds__(256) void scanC_kernel(
    const int* __restrict__ deg, int N, const int* __restrict__ bsum, int nbl,
    int E, int* __restrict__ rowptr, float* __restrict__ dinv)
{
    __shared__ int ws[4];
    __shared__ int sboff;
    int t = threadIdx.x;
    {
        int v = (t < nbl && t < blockIdx.x) ? bsum[t] : 0;
#pragma unroll
        for (int d = 1; d < 64; d <<= 1) v += __shfl_down(v, d, 64);
        int wid = t >> 6;
        if ((t & 63) == 0) ws[wid] = v;
        __syncthreads();
        if (t == 0) sboff = ws[0] + ws[1] + ws[2] + ws[3];
        __syncthreads();
    }

    int i = blockIdx.x * 256 + t;
    int d0 = (i < N) ? deg[i] : 0;
    int v = d0;
#pragma unroll
    for (int d = 1; d < 64; d <<= 1) {
        int u = __shfl_up(v, d, 64);
        if ((t & 63) >= d) v += u;
    }
    __shared__ int ws2[4];
    int wid = t >> 6;
    if ((t & 63) == 63) ws2[wid] = v;
    __syncthreads();
    int woff = 0;
    for (int w = 0; w < wid; ++w) woff += ws2[w];
    if (i < N) {
        rowptr[i] = sboff + woff + v - d0;
        dinv[i] = rsqrtf((float)d0 + 1.0f);
    }
    if (blockIdx.x == 0 && t == 0) rowptr[N] = E;
}

// ---------------------------------------------------------------------------
// 3) Build CSR slot arrays (no atomics: p = rowptr[r] + loc[i])
// ---------------------------------------------------------------------------
__global__ __launch_bounds__(256) void build_kernel(
    const int* __restrict__ ei, int E, const int* __restrict__ rowptr,
    const int* __restrict__ loc,
    int* __restrict__ eid_at_slot, int* __restrict__ col_sorted)
{
    int i = blockIdx.x * 256 + threadIdx.x;
    if (i >= E) return;
    int p = rowptr[ei[i]] + loc[i];
    eid_at_slot[p] = i;
    col_sorted[p] = ei[E + i];
}

// ---------------------------------------------------------------------------
// 4) ECC with MFMA einsum + segmented row reduction (CSR order).
//    Accumulators held in registers across all 4 m-tiles so lmsg can alias
//    the ENTIRE staging region (B + h2b + xb): LDS 35.3 -> 26.6 KB.
// ---------------------------------------------------------------------------
__global__ __launch_bounds__(256) void ecc_mfma_kernel(
    const float* __restrict__ e, const float* __restrict__ x,
    const int* __restrict__ eid_at_slot, const int* __restrict__ col_sorted,
    const int* __restrict__ rowptr, int N, int E,
    const float* __restrict__ w1, const float* __restrict__ b1,
    const float* __restrict__ w2, const float* __restrict__ b2,
    const float* __restrict__ w3, const float* __restrict__ b3,
    float* __restrict__ agg)
{
    // Layout: [0,12288) B bf16[6144] ; [12288,22528) h2b[256][20] ;
    //         [22528,26624) xb[256][8].  lmsg float[256][20] (20480 B)
    //         aliases [0,20480) after the MFMA phase.
    __shared__ char smem[26624];
    __shared__ int rbounds[2];
    unsigned short* Bl = (unsigned short*)smem;
    unsigned short (*h2b)[N_OUTC] = (unsigned short (*)[N_OUTC])(smem + 12288);
    unsigned short (*xb)[F_INN]   = (unsigned short (*)[F_INN])(smem + 22528);
    float* lmsg = (float*)smem;

    int t = threadIdx.x;
    int j0 = blockIdx.x * 256;
    int jend = min(j0 + 256, E);
    int j = j0 + t;

    if (t < 2) {
        int s = (t == 0) ? j0 : (jend - 1);
        int lo = 0, hi = N - 1;
        while (lo < hi) {
            int m = (lo + hi + 1) >> 1;
            if (rowptr[m] <= s) lo = m; else hi = m - 1;
        }
        rbounds[t] = lo;
    }

    // ---- stage B into LDS, fragment-ready: [s][nt][quad][n][j] (bf16) ----
    for (int idx = t; idx < 6144; idx += 256) {
        int jj   = idx & 7;
        int n    = (idx >> 3) & 15;
        int quad = (idx >> 7) & 3;
        int nt   = (idx >> 9) & 1;
        int s    = idx >> 10;
        int K = 32 * s + quad * 8 + jj;
        int o = n + 16 * nt;
        float v = 0.0f;
        if (o < N_OUTC) {
            if (K < 160)      v = w3[(K >> 3) * 160 + (K & 7) * N_OUTC + o];
            else if (K < 168) v = b3[(K - 160) * N_OUTC + o];
        }
        Bl[idx] = f2bf(v);
    }

    // ---- per-edge MLP (fp32) ----
    if (j < E) {
        int i = eid_at_slot[j];
        int c = col_sorted[j];

        float ef[S_DIM];
#pragma unroll
        for (int s = 0; s < S_DIM; ++s) ef[s] = e[(size_t)i * S_DIM + s];

        float h1[H_DIM];
#pragma unroll
        for (int jj = 0; jj < H_DIM; ++jj) {
            float a = b1[jj];
#pragma unroll
            for (int s = 0; s < S_DIM; ++s) a = fmaf(ef[s], w1[s * H_DIM + jj], a);
            h1[jj] = fmaxf(a, 0.0f);
        }

        float h2[H_DIM];
#pragma unroll
        for (int jj = 0; jj < H_DIM; ++jj) {
            float a = b2[jj];
#pragma unroll
            for (int k = 0; k < H_DIM; ++k) a = fmaf(h1[k], w2[k * H_DIM + jj], a);
            h2[jj] = fmaxf(a, 0.0f);
        }

        const float4* xp = (const float4*)&x[(size_t)c * F_INN];
        float4 xa = xp[0], xb4 = xp[1];
        float xf[F_INN] = {xa.x, xa.y, xa.z, xa.w, xb4.x, xb4.y, xb4.z, xb4.w};

#pragma unroll
        for (int o = 0; o < N_OUTC; ++o) h2b[t][o] = f2bf(h2[o]);
#pragma unroll
        for (int f = 0; f < F_INN; ++f) xb[t][f] = f2bf(xf[f]);
    } else {
#pragma unroll
        for (int o = 0; o < N_OUTC; ++o) h2b[t][o] = 0;
#pragma unroll
        for (int f = 0; f < F_INN; ++f) xb[t][f] = 0;
    }
    __syncthreads();

    // ---- load B fragments to registers ----
    int lane = t & 63;
    int quad = lane >> 4;
    int n = lane & 15;
    short8 Bf[12];
#pragma unroll
    for (int s = 0; s < 6; ++s)
#pragma unroll
        for (int nt = 0; nt < 2; ++nt)
            Bf[s * 2 + nt] = *(const short8*)&Bl[((((s * 2 + nt) * 4 + quad) * 16 + n) * 8)];

    // ---- MFMA: 4 m-tiles per wave, accs in registers ----
    int w = t >> 6;
    floatx4 acc0s[4], acc1s[4];
#pragma unroll
    for (int T = 0; T < 4; ++T) {
        int base = w * 64 + T * 16;
        int m = base + n;

        const short8 xv8 = *(const short8*)&xb[m][0];
        float xfl[F_INN];
#pragma unroll
        for (int jj = 0; jj < F_INN; ++jj) xfl[jj] = bf2f((unsigned short)xv8[jj]);

        floatx4 acc0 = {0.f, 0.f, 0.f, 0.f};
        floatx4 acc1 = {0.f, 0.f, 0.f, 0.f};
#pragma unroll
        for (int s = 0; s < 6; ++s) {
            short8 A = {0, 0, 0, 0, 0, 0, 0, 0};
            if (s < 5) {
                float h = bf2f(h2b[m][4 * s + quad]);
#pragma unroll
                for (int jj = 0; jj < F_INN; ++jj)
                    A[jj] = (short)f2bf(h * xfl[jj]);
            } else if (quad == 0) {
                A = xv8;                        // b3 rows: p = x
            }
            acc0 = __builtin_amdgcn_mfma_f32_16x16x32_bf16(A, Bf[s * 2 + 0], acc0, 0, 0, 0);
            acc1 = __builtin_amdgcn_mfma_f32_16x16x32_bf16(A, Bf[s * 2 + 1], acc1, 0, 0, 0);
        }
        acc0s[T] = acc0;
        acc1s[T] = acc1;
    }
    __syncthreads();   // all LDS reads done -> lmsg may overwrite everything

    // ---- C-write: col = n (+16 for acc1), row = base + quad*4 + r ----
#pragma unroll
    for (int T = 0; T < 4; ++T) {
        int base = w * 64 + T * 16;
#pragma unroll
        for (int r = 0; r < 4; ++r) {
            int row = base + quad * 4 + r;
            lmsg[row * N_OUTC + n] = acc0s[T][r];
            if (n < 4) lmsg[row * N_OUTC + 16 + n] = acc1s[T][r];
        }
    }
    __syncthreads();

    // ---- segmented row reduction into agg ----
    int r0 = rbounds[0], r1 = rbounds[1];
    int work = (r1 - r0 + 1) * 5;
    for (int ww = t; ww < work; ww += 256) {
        int row = r0 + ww / 5;
        int q = ww - (ww / 5) * 5;
        int a0 = rowptr[row], a1 = rowptr[row + 1];
        int s0 = max(a0, j0), s1 = min(a1, jend);
        float4 acc = make_float4(0.f, 0.f, 0.f, 0.f);
        for (int s = s0; s < s1; ++s) {
            const float4 v = *(const float4*)&lmsg[(s - j0) * N_OUTC + q * 4];
            acc.x += v.x; acc.y += v.y; acc.z += v.z; acc.w += v.w;
        }
        float* dst = &agg[(size_t)row * N_OUTC + q * 4];
        if (a0 >= j0 && a1 <= jend) {
            *(float4*)dst = acc;
        } else {
            unsafeAtomicAdd(dst + 0, acc.x);
            unsafeAtomicAdd(dst + 1, acc.y);
            unsafeAtomicAdd(dst + 2, acc.z);
            unsafeAtomicAdd(dst + 3, acc.w);
        }
    }
}

// ---------------------------------------------------------------------------
// 5) Node transform: x1 = relu(agg + x@root + b);
//    hws1 = bf16( dinv * (x1 @ gcn1_w) )
// ---------------------------------------------------------------------------
__global__ __launch_bounds__(256) void node1_kernel(
    const float* __restrict__ agg, const float* __restrict__ x,
    const float* __restrict__ dinv, int N,
    const float* __restrict__ root, const float* __restrict__ eb,
    const float* __restrict__ g1w,
    unsigned short* __restrict__ hws1)
{
    int n = blockIdx.x * 256 + threadIdx.x;
    if (n >= N) return;

    const float4* xp = (const float4*)&x[(size_t)n * F_INN];
    float4 xa = xp[0], xb = xp[1];
    float xf[F_INN] = {xa.x, xa.y, xa.z, xa.w, xb.x, xb.y, xb.z, xb.w};

    float x1[N_OUTC];
#pragma unroll
    for (int o = 0; o < N_OUTC; ++o) {
        float a = agg[(size_t)n * N_OUTC + o] + eb[o];
#pragma unroll
        for (int f = 0; f < F_INN; ++f) a = fmaf(xf[f], root[f * N_OUTC + o], a);
        x1[o] = fmaxf(a, 0.0f);
    }

    float di = dinv[n];
#pragma unroll
    for (int q = 0; q < 4; ++q) {
        short8 o8;
#pragma unroll
        for (int u = 0; u < 8; ++u) {
            int g = q * 8 + u;
            float a = 0.0f;
#pragma unroll
            for (int o = 0; o < N_OUTC; ++o) a = fmaf(x1[o], g1w[o * G_DIM + g], a);
            o8[u] = (short)f2bf(a * di);
        }
        *(short8*)&hws1[(size_t)n * G_DIM + q * 8] = o8;
    }
}

// ---------------------------------------------------------------------------
// 6) GCN gather on pre-scaled bf16 features. Thread = (node, chunk of 4);
//    each thread handles 8 channels (one 16B bf16 load per neighbor).
//    x' = relu(di*(Σ hws[c] + hws[n]) + b).
//    DO_MATMUL: fused @W2 epilogue via LDS; output bf16( di * x2@W2 ).
// ---------------------------------------------------------------------------
template<bool DO_MATMUL>
__global__ __launch_bounds__(256) void gcn_gather_kernel(
    const unsigned short* __restrict__ hws, const int* __restrict__ rowptr,
    const int* __restrict__ col_sorted, const float* __restrict__ dinv, int N,
    const float* __restrict__ bias, const float* __restrict__ w2,
    unsigned short* __restrict__ outbuf)
{
    __shared__ float x2s[64][33];
    __shared__ float w2s[G_DIM * G_DIM];

    int t = threadIdx.x;
    int nl = t >> 2;
    int q = t & 3;
    int n = blockIdx.x * 64 + nl;

    if (DO_MATMUL) {
        ((float4*)w2s)[t] = ((const float4*)w2)[t];
    }

    float xo[8];
    float di = 0.0f;
    if (n < N) {
        di = dinv[n];
        int j0 = rowptr[n], j1 = rowptr[n + 1];
        short8 sv = *(const short8*)&hws[(size_t)n * G_DIM + q * 8];
        float s[8];
#pragma unroll
        for (int k = 0; k < 8; ++k) s[k] = bf2f((unsigned short)sv[k]);
        for (int j = j0; j < j1; ++j) {
            int c = col_sorted[j];
            short8 v = *(const short8*)&hws[(size_t)c * G_DIM + q * 8];
#pragma unroll
            for (int k = 0; k < 8; ++k) s[k] += bf2f((unsigned short)v[k]);
        }
#pragma unroll
        for (int k = 0; k < 8; ++k)
            xo[k] = fmaxf(fmaf(di, s[k], bias[q * 8 + k]), 0.0f);
    } else {
#pragma unroll
        for (int k = 0; k < 8; ++k) xo[k] = 0.0f;
    }

    if (DO_MATMUL) {
#pragma unroll
        for (int k = 0; k < 8; ++k) x2s[nl][q * 8 + k] = xo[k];
        __syncthreads();
        if (n < N) {
            float a[8];
#pragma unroll
            for (int k = 0; k < 8; ++k) a[k] = 0.0f;
#pragma unroll
            for (int g = 0; g < G_DIM; ++g) {
                float xv = x2s[nl][g];
#pragma unroll
                for (int k = 0; k < 8; ++k)
                    a[k] = fmaf(xv, w2s[g * G_DIM + q * 8 + k], a[k]);
            }
            short8 o8;
#pragma unroll
            for (int k = 0; k < 8; ++k) o8[k] = (short)f2bf(a[k] * di);
            *(short8*)&outbuf[(size_t)n * G_DIM + q * 8] = o8;
        }
    } else {
        if (n < N) {
            short8 o8;
#pragma unroll
            for (int k = 0; k < 8; ++k) o8[k] = (short)f2bf(xo[k]);
            *(short8*)&outbuf[(size_t)n * G_DIM + q * 8] = o8;
        }
    }
}

// ---------------------------------------------------------------------------
// 7) Pool + head fused (x3 is bf16)
// ---------------------------------------------------------------------------
__global__ __launch_bounds__(256) void pool_head_kernel(
    const unsigned short* __restrict__ x3, const int* __restrict__ seg, int N,
    const float* __restrict__ d1w, const float* __restrict__ d1b,
    const float* __restrict__ d2w, const float* __restrict__ d2b,
    float* __restrict__ out)
{
    __shared__ float red[8][G_DIM];
    __shared__ float pvec[G_DIM];
    __shared__ int bounds[2];
    int g = blockIdx.x;
    int t = threadIdx.x;
    if (t < 2) {
        int target = g + t;
        int lo = 0, hi = N;
        while (lo < hi) {
            int m = (lo + hi) >> 1;
            if (seg[m] < target) lo = m + 1; else hi = m;
        }
        bounds[t] = lo;
    }
    __syncthreads();
    int n0 = bounds[0], n1 = bounds[1];
    int ch = t & (G_DIM - 1);
    int slice = t >> 5;
    float a = 0.0f;
    for (int n = n0 + slice; n < n1; n += 8)
        a += bf2f(x3[(size_t)n * G_DIM + ch]);
    red[slice][ch] = a;
    __syncthreads();
    if (slice == 0) {
        float s = red[0][ch];
#pragma unroll
        for (int k = 1; k < 8; ++k) s += red[k][ch];
        pvec[ch] = s;
    }
    __syncthreads();
    if (t < 64) {
        float acc = 0.0f;
        if (t < D1_DIM) {
            float tj = d1b[t];
#pragma unroll
            for (int gg = 0; gg < G_DIM; ++gg)
                tj = fmaf(pvec[gg], d1w[gg * D1_DIM + t], tj);
            acc = tj * d2w[t];
        }
#pragma unroll
        for (int d = 1; d < D1_DIM; d <<= 1) acc += __shfl_down(acc, d, 64);
        if (t == 0) out[g] = acc + d2b[0];
    }
}

// ---------------------------------------------------------------------------
extern "C" void kernel_launch(void* const* d_in, const int* in_sizes, int n_in,
                              void* d_out, int out_size, void* d_ws, size_t ws_size,
                              hipStream_t stream)
{
    const float* x    = (const float*)d_in[0];
    const float* e    = (const float*)d_in[1];
    const int*   ei   = (const int*)d_in[2];
    const int*   seg  = (const int*)d_in[3];
    const float* w1   = (const float*)d_in[4];
    const float* b1   = (const float*)d_in[5];
    const float* w2   = (const float*)d_in[6];
    const float* b2   = (const float*)d_in[7];
    const float* w3   = (const float*)d_in[8];
    const float* b3   = (const float*)d_in[9];
    const float* root = (const float*)d_in[10];
    const float* eb   = (const float*)d_in[11];
    const float* g1w  = (const float*)d_in[12];
    const float* g1b  = (const float*)d_in[13];
    const float* g2w  = (const float*)d_in[14];
    const float* g2b  = (const float*)d_in[15];
    const float* d1w  = (const float*)d_in[16];
    const float* d1b  = (const float*)d_in[17];
    const float* d2w  = (const float*)d_in[18];
    const float* d2b  = (const float*)d_in[19];

    const int N = in_sizes[3];            // 50000
    const int E = in_sizes[1] / S_DIM;    // 800000
    float* out = (float*)d_out;

    const int nbl = (N + 255) / 256;      // 196 (<= 256 for scanC)
    const int ebl = (E + 255) / 256;

    char* ws = (char*)d_ws;
    size_t off = 0;
    auto alloc = [&](size_t elems) -> char* {
        char* p = ws + off;
        off += ((elems * 4 + 15) & ~(size_t)15);
        return p;
    };
    int*   cnt        = (int*)  alloc(N);                    // zeroed (deg)
    float* agg        = (float*)alloc((size_t)N * N_OUTC);   // zeroed
    size_t zero_bytes = off;
    int*   rowptr     = (int*)  alloc(N + 1);
    int*   bsum       = (int*)  alloc(nbl);
    float* dinv       = (float*)alloc(N);
    int*   loc        = (int*)  alloc(E);
    int*   eid_at_slot= (int*)  alloc(E);
    int*   col_sorted = (int*)  alloc(E);
    unsigned short* hws1 = (unsigned short*)alloc((size_t)N * G_DIM / 2);
    unsigned short* hws2 = (unsigned short*)alloc((size_t)N * G_DIM / 2);
    unsigned short* x3   = (unsigned short*)alloc((size_t)N * G_DIM / 2);
    (void)ws_size;

    hipMemsetAsync(d_ws, 0, zero_bytes, stream);

    loc_kernel<<<ebl, 256, 0, stream>>>(ei, E, cnt, loc);
    scanA_kernel<<<nbl, 256, 0, stream>>>(cnt, N, bsum);
    scanC_kernel<<<nbl, 256, 0, stream>>>(cnt, N, bsum, nbl, E, rowptr, dinv);
    build_kernel<<<ebl, 256, 0, stream>>>(ei, E, rowptr, loc, eid_at_slot, col_sorted);
    ecc_mfma_kernel<<<ebl, 256, 0, stream>>>(e, x, eid_at_slot, col_sorted,
                                             rowptr, N, E,
                                             w1, b1, w2, b2, w3, b3, agg);
    node1_kernel<<<nbl, 256, 0, stream>>>(agg, x, dinv, N, root, eb, g1w, hws1);
    gcn_gather_kernel<true><<<(N + 63) / 64, 256, 0, stream>>>(
        hws1, rowptr, col_sorted, dinv, N, g1b, g2w, hws2);
    gcn_gather_kernel<false><<<(N + 63) / 64, 256, 0, stream>>>(
        hws2, rowptr, col_sorted, dinv, N, g2b, nullptr, x3);
    pool_head_kernel<<<NGRAPH, 256, 0, stream>>>(x3, seg, N, d1w, d1b, d2w, d2b, out);
}